// Round 1
// baseline (4822.078 us; speedup 1.0000x reference)
//
#include <hip/hip_runtime.h>
#include <hip/hip_bf16.h>
#include <math.h>

#define B_ 32
#define N_ 784
#define C_ 576
#define H_ 28
#define W_ 28
#define HEADS_ 8
#define HD_ 72
#define AGENT_ 49
#define M_ (B_ * N_)            // 25088
#define KTOT_ 5184              // 576 silu + 576*8 spline
#define SCALE_ 0.11785113019775793f

// ws offsets (floats)
#define OFF_Q      0ull
#define OFF_K      14450688ull
#define OFF_V      28901376ull
#define OFF_AGENT  43352064ull
#define OFF_AGENTV 44255232ull
#define OFF_ABIAS  45158400ull
#define OFF_QBIAS  45465728ull
#define OFF_XF     45773056ull
#define OFF_BPACK  60223744ull
// total end: 63,209,728 floats = 252.8 MB

// ---------------- pack B for the KAN gemm ----------------
__global__ __launch_bounds__(256) void pack_b_kernel(
    const float* __restrict__ base_w, const float* __restrict__ spline_w,
    const float* __restrict__ spline_s, float* __restrict__ bpack) {
  int o = blockIdx.x;
  for (int j = threadIdx.x; j < KTOT_; j += 256) {
    float v;
    if (j < C_) {
      v = base_w[(size_t)o * C_ + j];
    } else {
      int jj = j - C_;
      int i = jj >> 3, kk = jj & 7;
      v = spline_w[((size_t)o * C_ + i) * 8 + kk] * spline_s[(size_t)o * C_ + i];
    }
    bpack[(size_t)o * KTOT_ + j] = v;
  }
}

// ---------------- bias precompute (bilinear resize + additive biases) ----------------
__device__ __forceinline__ float bilerp7(const float* __restrict__ Bsrc, int y, int x) {
  float sy = y * 0.25f - 0.375f;
  float sx = x * 0.25f - 0.375f;
  float fy0 = floorf(sy), fx0 = floorf(sx);
  int y0 = (int)fy0, x0 = (int)fx0;
  float fy = sy - fy0, fx = sx - fx0;
  int y0c = min(6, max(0, y0)), y1c = min(6, max(0, y0 + 1));
  int x0c = min(6, max(0, x0)), x1c = min(6, max(0, x0 + 1));
  float v00 = Bsrc[y0c * 7 + x0c], v01 = Bsrc[y0c * 7 + x1c];
  float v10 = Bsrc[y1c * 7 + x0c], v11 = Bsrc[y1c * 7 + x1c];
  return (1.f - fy) * ((1.f - fx) * v00 + fx * v01)
       + fy * ((1.f - fx) * v10 + fx * v11);
}

__global__ __launch_bounds__(256) void bias_kernel(
    const float* __restrict__ an_bias, const float* __restrict__ na_bias,
    const float* __restrict__ ah_bias, const float* __restrict__ aw_bias,
    const float* __restrict__ ha_bias, const float* __restrict__ wa_bias,
    float* __restrict__ abias, float* __restrict__ qbias) {
  int idx = blockIdx.x * 256 + threadIdx.x;
  if (idx >= HEADS_ * AGENT_ * N_) return;
  int n = idx % N_;
  int ha = idx / N_;               // h*49 + a
  int h = ha / AGENT_, a = ha % AGENT_;
  int y = n / W_, x = n % W_;
  float pb1 = bilerp7(an_bias + (size_t)ha * 49, y, x);
  float pb2 = ah_bias[ha * H_ + y] + aw_bias[ha * W_ + x];
  abias[(size_t)ha * N_ + n] = pb1 + pb2;
  float ab1 = bilerp7(na_bias + (size_t)ha * 49, y, x);
  float ab2 = ha_bias[(h * H_ + y) * AGENT_ + a] + wa_bias[(h * W_ + x) * AGENT_ + a];
  qbias[((size_t)h * N_ + n) * AGENT_ + a] = ab1 + ab2;
}

// ---------------- fused q/k/v GEMM:  C[m,j] = sum_k x[m,k]*W[j,k] ----------------
__global__ __launch_bounds__(256) void gemm_qkv_kernel(
    const float* __restrict__ x, const float* __restrict__ Wq,
    const float* __restrict__ Wkv, float* __restrict__ qo,
    float* __restrict__ ko, float* __restrict__ vo) {
  __shared__ float As[16][68];
  __shared__ float Bs[16][68];
  const int tid = threadIdx.x;
  const int tx = tid & 15, ty = tid >> 4;
  const int m0 = blockIdx.y * 64, j0 = blockIdx.x * 64;
  const int lrow = tid >> 2, lcol = (tid & 3) * 4;
  const float* arow = x + (size_t)(m0 + lrow) * C_;
  const int jrow = j0 + lrow;
  const float* brow = (jrow < C_) ? (Wq + (size_t)jrow * C_)
                                  : (Wkv + (size_t)(jrow - C_) * C_);
  float acc[4][4] = {};
  for (int k0 = 0; k0 < C_; k0 += 16) {
    float4 a4 = *(const float4*)(arow + k0 + lcol);
    float4 b4 = *(const float4*)(brow + k0 + lcol);
    __syncthreads();
    As[lcol + 0][lrow] = a4.x; As[lcol + 1][lrow] = a4.y;
    As[lcol + 2][lrow] = a4.z; As[lcol + 3][lrow] = a4.w;
    Bs[lcol + 0][lrow] = b4.x; Bs[lcol + 1][lrow] = b4.y;
    Bs[lcol + 2][lrow] = b4.z; Bs[lcol + 3][lrow] = b4.w;
    __syncthreads();
    #pragma unroll
    for (int kk = 0; kk < 16; ++kk) {
      float4 av = *(const float4*)&As[kk][ty * 4];
      float4 bv = *(const float4*)&Bs[kk][tx * 4];
      float ar[4] = {av.x, av.y, av.z, av.w};
      float br[4] = {bv.x, bv.y, bv.z, bv.w};
      #pragma unroll
      for (int i = 0; i < 4; ++i)
        #pragma unroll
        for (int j2 = 0; j2 < 4; ++j2)
          acc[i][j2] += ar[i] * br[j2];
    }
  }
  const int mo = m0 + ty * 4;
  const int jo = j0 + tx * 4;
  #pragma unroll
  for (int i = 0; i < 4; ++i) {
    float4 val = make_float4(acc[i][0], acc[i][1], acc[i][2], acc[i][3]);
    size_t ro = (size_t)(mo + i) * C_;
    if (jo < C_)           *(float4*)(qo + ro + jo) = val;
    else if (jo < 2 * C_)  *(float4*)(ko + ro + (jo - C_)) = val;
    else                   *(float4*)(vo + ro + (jo - 2 * C_)) = val;
  }
}

// ---------------- agent pooling: 4x4 block mean of q ----------------
__global__ __launch_bounds__(576) void agent_pool_kernel(
    const float* __restrict__ q, float* __restrict__ agent) {
  int ba = blockIdx.x;                 // b*49 + a
  int b = ba / AGENT_, a = ba % AGENT_;
  int ay = a / 7, ax = a % 7;
  int ch = threadIdx.x;
  float s = 0.f;
  #pragma unroll
  for (int i2 = 0; i2 < 4; ++i2)
    #pragma unroll
    for (int i4 = 0; i4 < 4; ++i4)
      s += q[((size_t)b * N_ + (ay * 4 + i2) * W_ + (ax * 4 + i4)) * C_ + ch];
  agent[(size_t)ba * C_ + ch] = s * 0.0625f;
}

// ---------------- agent attention: softmax_n(scale*ah.k + bias) @ v ----------------
__global__ __launch_bounds__(256) void agent_attn_kernel(
    const float* __restrict__ agent, const float* __restrict__ kmat,
    const float* __restrict__ vmat, const float* __restrict__ abias,
    float* __restrict__ agent_v) {
  __shared__ float ah_s[HD_];
  __shared__ float p_s[N_];
  __shared__ float red[256];
  __shared__ float pv_s[216];
  const int tid = threadIdx.x;
  const int bh = blockIdx.x / AGENT_, a = blockIdx.x % AGENT_;
  const int b = bh >> 3, h = bh & 7;
  if (tid < HD_) ah_s[tid] = agent[((size_t)b * AGENT_ + a) * C_ + h * HD_ + tid];
  __syncthreads();
  float lmax = -1e30f;
  for (int n = tid; n < N_; n += 256) {
    const float* kp = kmat + ((size_t)b * N_ + n) * C_ + h * HD_;
    float dot = 0.f;
    #pragma unroll
    for (int d4 = 0; d4 < HD_ / 4; ++d4) {
      float4 a4 = *(const float4*)&ah_s[d4 * 4];
      float4 k4 = *(const float4*)&kp[d4 * 4];
      dot += a4.x * k4.x + a4.y * k4.y + a4.z * k4.z + a4.w * k4.w;
    }
    float lg = dot * SCALE_ + abias[((size_t)h * AGENT_ + a) * N_ + n];
    p_s[n] = lg;
    lmax = fmaxf(lmax, lg);
  }
  red[tid] = lmax;
  __syncthreads();
  for (int s2 = 128; s2 > 0; s2 >>= 1) {
    if (tid < s2) red[tid] = fmaxf(red[tid], red[tid + s2]);
    __syncthreads();
  }
  float mx = red[0];
  __syncthreads();
  float lsum = 0.f;
  for (int n = tid; n < N_; n += 256) {
    float e = expf(p_s[n] - mx);
    p_s[n] = e;
    lsum += e;
  }
  red[tid] = lsum;
  __syncthreads();
  for (int s2 = 128; s2 > 0; s2 >>= 1) {
    if (tid < s2) red[tid] += red[tid + s2];
    __syncthreads();
  }
  float inv = 1.f / red[0];
  if (tid < 216) {
    int d = tid % HD_, seg = tid / HD_;
    float acc = 0.f;
    for (int n = seg; n < N_; n += 3)
      acc += p_s[n] * vmat[((size_t)b * N_ + n) * C_ + h * HD_ + d];
    pv_s[tid] = acc;
  }
  __syncthreads();
  if (tid < HD_) {
    float r = (pv_s[tid] + pv_s[72 + tid] + pv_s[144 + tid]) * inv;
    agent_v[(size_t)blockIdx.x * HD_ + tid] = r;
  }
}

// ---------------- q attention: softmax_a(scale*q.ah + bias) @ agent_v ----------------
__global__ __launch_bounds__(256) void q_attn_kernel(
    const float* __restrict__ q, const float* __restrict__ agent,
    const float* __restrict__ agent_v, const float* __restrict__ qbias,
    float* __restrict__ xf) {
  __shared__ float ag_t[HD_ * 52];   // [d][a] padded
  __shared__ float av_t[HD_ * 52];
  const int tid = threadIdx.x;
  const int h = blockIdx.y, b = blockIdx.z;
  for (int t = tid; t < AGENT_ * HD_; t += 256) {
    int a = t / HD_, d = t % HD_;
    ag_t[d * 52 + a] = agent[((size_t)b * AGENT_ + a) * C_ + h * HD_ + d];
    av_t[d * 52 + a] = agent_v[(((size_t)b * HEADS_ + h) * AGENT_ + a) * HD_ + d];
  }
  __syncthreads();
  const int n = blockIdx.x * 256 + tid;
  if (n >= N_) return;
  const float* qp = q + ((size_t)b * N_ + n) * C_ + h * HD_;
  const float* qb = qbias + ((size_t)h * N_ + n) * AGENT_;
  float lg[AGENT_];
  #pragma unroll
  for (int a = 0; a < AGENT_; ++a) lg[a] = qb[a];
  for (int d = 0; d < HD_; ++d) {
    float qd = qp[d] * SCALE_;
    #pragma unroll
    for (int a = 0; a < AGENT_; ++a) lg[a] += qd * ag_t[d * 52 + a];
  }
  float mx = -1e30f;
  #pragma unroll
  for (int a = 0; a < AGENT_; ++a) mx = fmaxf(mx, lg[a]);
  float s = 0.f;
  #pragma unroll
  for (int a = 0; a < AGENT_; ++a) { lg[a] = expf(lg[a] - mx); s += lg[a]; }
  float inv = 1.f / s;
  #pragma unroll
  for (int a = 0; a < AGENT_; ++a) lg[a] *= inv;
  float* op = xf + ((size_t)b * N_ + n) * C_ + h * HD_;
  for (int d = 0; d < HD_; ++d) {
    float acc = 0.f;
    #pragma unroll
    for (int a = 0; a < AGENT_; ++a) acc += lg[a] * av_t[d * 52 + a];
    op[d] = acc;
  }
}

// ---------------- depthwise conv 3x3 + BN + ReLU, added into xf ----------------
__global__ __launch_bounds__(576) void dwc_kernel(
    const float* __restrict__ vmat, const float* __restrict__ w,
    const float* __restrict__ bias, const float* __restrict__ gamma,
    const float* __restrict__ beta, const float* __restrict__ mean,
    const float* __restrict__ var, float* __restrict__ xf) {
  const int bn = blockIdx.x;         // b*784 + n
  const int b = bn / N_, n = bn % N_;
  const int y = n / W_, x = n % W_;
  const int ch = threadIdx.x;
  float acc = 0.f;
  #pragma unroll
  for (int ky = 0; ky < 3; ++ky) {
    int yy = y + ky - 1;
    if (yy < 0 || yy >= H_) continue;
    #pragma unroll
    for (int kx = 0; kx < 3; ++kx) {
      int xx = x + kx - 1;
      if (xx < 0 || xx >= W_) continue;
      acc += w[ch * 9 + ky * 3 + kx] * vmat[((size_t)b * N_ + yy * W_ + xx) * C_ + ch];
    }
  }
  float sc = gamma[ch] * rsqrtf(var[ch] + 1e-5f);
  float val = (acc + bias[ch] - mean[ch]) * sc + beta[ch];
  xf[(size_t)bn * C_ + ch] += fmaxf(val, 0.f);
}

// ---------------- KAN gemm: out[m,o] = sum_j A(m,j)*Bpack[o,j] ----------------
__device__ __forceinline__ float silu_f(float v) { return v / (1.f + expf(-v)); }

__global__ __launch_bounds__(256) void kan_gemm_kernel(
    const float* __restrict__ xf, const float* __restrict__ bpack,
    float* __restrict__ out) {
  __shared__ float As[16][68];
  __shared__ float Bs[16][68];
  const int tid = threadIdx.x;
  const int tx = tid & 15, ty = tid >> 4;
  const int m0 = blockIdx.y * 64, o0 = blockIdx.x * 64;
  const int lrow = tid >> 2, lcol = (tid & 3) * 4;
  const float* xrow = xf + (size_t)(m0 + lrow) * C_;
  const float* brow = bpack + (size_t)(o0 + lrow) * KTOT_;
  float acc[4][4] = {};
  for (int k0 = 0; k0 < KTOT_; k0 += 16) {
    int kg = k0 + lcol;
    float av[4];
    if (kg < C_) {
      float4 t4 = *(const float4*)(xrow + kg);
      av[0] = silu_f(t4.x); av[1] = silu_f(t4.y);
      av[2] = silu_f(t4.z); av[3] = silu_f(t4.w);
    } else {
      int jj = kg - C_;
      float xv = xrow[jj >> 3];
      int s0 = jj & 7;                       // 0 or 4
      float tc = floorf((xv + 2.2f) * 2.5f); // cell index, h = 0.4
      int t = (int)tc;
      float u = (xv + 2.2f) * 2.5f - tc;
      float u2 = u * u, u3 = u2 * u, um = 1.f - u;
      float p0 = u3 * (1.f / 6.f);
      float p1 = (-3.f * u3 + 3.f * u2 + 3.f * u + 1.f) * (1.f / 6.f);
      float p2 = (3.f * u3 - 6.f * u2 + 4.f) * (1.f / 6.f);
      float p3 = um * um * um * (1.f / 6.f);
      bool inr = (t >= 0) && (t <= 10);
      #pragma unroll
      for (int e = 0; e < 4; ++e) {
        int j2 = s0 + e;                     // basis index 0..7
        float r = 0.f;
        r = (j2 == t - 3) ? p3 : r;
        r = (j2 == t - 2) ? p2 : r;
        r = (j2 == t - 1) ? p1 : r;
        r = (j2 == t)     ? p0 : r;
        av[e] = inr ? r : 0.f;
      }
    }
    float4 b4 = *(const float4*)(brow + k0 + lcol);
    __syncthreads();
    As[lcol + 0][lrow] = av[0]; As[lcol + 1][lrow] = av[1];
    As[lcol + 2][lrow] = av[2]; As[lcol + 3][lrow] = av[3];
    Bs[lcol + 0][lrow] = b4.x;  Bs[lcol + 1][lrow] = b4.y;
    Bs[lcol + 2][lrow] = b4.z;  Bs[lcol + 3][lrow] = b4.w;
    __syncthreads();
    #pragma unroll
    for (int kk = 0; kk < 16; ++kk) {
      float4 avv = *(const float4*)&As[kk][ty * 4];
      float4 bvv = *(const float4*)&Bs[kk][tx * 4];
      float ar[4] = {avv.x, avv.y, avv.z, avv.w};
      float br[4] = {bvv.x, bvv.y, bvv.z, bvv.w};
      #pragma unroll
      for (int i = 0; i < 4; ++i)
        #pragma unroll
        for (int j2 = 0; j2 < 4; ++j2)
          acc[i][j2] += ar[i] * br[j2];
    }
  }
  const int mo = m0 + ty * 4;
  const int oo = o0 + tx * 4;
  #pragma unroll
  for (int i = 0; i < 4; ++i) {
    float4 val = make_float4(acc[i][0], acc[i][1], acc[i][2], acc[i][3]);
    *(float4*)(out + (size_t)(mo + i) * C_ + oo) = val;
  }
}

extern "C" void kernel_launch(void* const* d_in, const int* in_sizes, int n_in,
                              void* d_out, int out_size, void* d_ws, size_t ws_size,
                              hipStream_t stream) {
  const float* x        = (const float*)d_in[0];
  const float* Wq       = (const float*)d_in[3];
  const float* Wkv      = (const float*)d_in[4];
  const float* an_bias  = (const float*)d_in[5];
  const float* na_bias  = (const float*)d_in[6];
  const float* ah_bias  = (const float*)d_in[7];
  const float* aw_bias  = (const float*)d_in[8];
  const float* ha_bias  = (const float*)d_in[9];
  const float* wa_bias  = (const float*)d_in[10];
  const float* dwc_w    = (const float*)d_in[11];
  const float* dwc_b    = (const float*)d_in[12];
  const float* bn_gamma = (const float*)d_in[13];
  const float* bn_beta  = (const float*)d_in[14];
  const float* bn_mean  = (const float*)d_in[15];
  const float* bn_var   = (const float*)d_in[16];
  const float* base_w   = (const float*)d_in[17];
  const float* spline_w = (const float*)d_in[18];
  const float* spline_s = (const float*)d_in[19];

  float* ws = (float*)d_ws;
  float* q       = ws + OFF_Q;
  float* k       = ws + OFF_K;
  float* v       = ws + OFF_V;
  float* agent   = ws + OFF_AGENT;
  float* agent_v = ws + OFF_AGENTV;
  float* abias   = ws + OFF_ABIAS;
  float* qbias   = ws + OFF_QBIAS;
  float* xf      = ws + OFF_XF;
  float* bpack   = ws + OFF_BPACK;
  float* out     = (float*)d_out;

  pack_b_kernel<<<dim3(C_), dim3(256), 0, stream>>>(base_w, spline_w, spline_s, bpack);
  bias_kernel<<<dim3((HEADS_ * AGENT_ * N_ + 255) / 256), dim3(256), 0, stream>>>(
      an_bias, na_bias, ah_bias, aw_bias, ha_bias, wa_bias, abias, qbias);
  gemm_qkv_kernel<<<dim3(27, 392), dim3(256), 0, stream>>>(x, Wq, Wkv, q, k, v);
  agent_pool_kernel<<<dim3(B_ * AGENT_), dim3(C_), 0, stream>>>(q, agent);
  agent_attn_kernel<<<dim3(B_ * HEADS_ * AGENT_), dim3(256), 0, stream>>>(
      agent, k, v, abias, agent_v);
  q_attn_kernel<<<dim3(4, HEADS_, B_), dim3(256), 0, stream>>>(
      q, agent, agent_v, qbias, xf);
  dwc_kernel<<<dim3(M_), dim3(C_), 0, stream>>>(
      v, dwc_w, dwc_b, bn_gamma, bn_beta, bn_mean, bn_var, xf);
  kan_gemm_kernel<<<dim3(9, 392), dim3(256), 0, stream>>>(xf, bpack, out);
}

// Round 2
// 1760.376 us; speedup vs baseline: 2.7392x; 2.7392x over previous
//
#include <hip/hip_runtime.h>
#include <hip/hip_bf16.h>
#include <math.h>

#define B_ 32
#define N_ 784
#define C_ 576
#define H_ 28
#define W_ 28
#define HEADS_ 8
#define HD_ 72
#define AGENT_ 49
#define M_ (B_ * N_)            // 25088
#define KTOT_ 5184              // 576 silu + 576*8 spline
#define QKVW_ 1728
#define SCALE_ 0.11785113019775793f

typedef unsigned short ushort_t;
typedef __attribute__((ext_vector_type(8))) unsigned short u16x8;
typedef __attribute__((ext_vector_type(8))) __bf16 bf16x8;
typedef __attribute__((ext_vector_type(4))) float f32x4;

__device__ __forceinline__ ushort_t f2bf(float f) {
  union { float f; unsigned u; } v; v.f = f;
  unsigned r = v.u + 0x7fffu + ((v.u >> 16) & 1u);
  return (ushort_t)(r >> 16);
}
__device__ __forceinline__ float bf2f(ushort_t u) {
  union { unsigned u; float f; } v; v.u = ((unsigned)u) << 16;
  return v.f;
}

// ---------------- converts / packs ----------------
__global__ __launch_bounds__(256) void convert_x_kernel(
    const float* __restrict__ x, ushort_t* __restrict__ xbf) {
  const int total8 = M_ * C_ / 8;
  for (int i = blockIdx.x * 256 + threadIdx.x; i < total8; i += gridDim.x * 256) {
    f32x4 a = *(const f32x4*)(x + i * 8);
    f32x4 b = *(const f32x4*)(x + i * 8 + 4);
    u16x8 o;
    o[0]=f2bf(a[0]); o[1]=f2bf(a[1]); o[2]=f2bf(a[2]); o[3]=f2bf(a[3]);
    o[4]=f2bf(b[0]); o[5]=f2bf(b[1]); o[6]=f2bf(b[2]); o[7]=f2bf(b[3]);
    *(u16x8*)(xbf + i * 8) = o;
  }
}

__global__ __launch_bounds__(256) void pack_w_kernel(
    const float* __restrict__ Wq, const float* __restrict__ Wkv,
    ushort_t* __restrict__ wbf) {
  int total = QKVW_ * C_;
  for (int i = blockIdx.x * 256 + threadIdx.x; i < total; i += gridDim.x * 256) {
    int j = i / C_, k = i % C_;
    float v = (j < C_) ? Wq[(size_t)j * C_ + k] : Wkv[(size_t)(j - C_) * C_ + k];
    wbf[i] = f2bf(v);
  }
}

__global__ __launch_bounds__(256) void pack_b_kernel(
    const float* __restrict__ base_w, const float* __restrict__ spline_w,
    const float* __restrict__ spline_s, ushort_t* __restrict__ bpackb) {
  int o = blockIdx.x;
  for (int j = threadIdx.x; j < KTOT_; j += 256) {
    float v;
    if (j < C_) {
      v = base_w[(size_t)o * C_ + j];
    } else {
      int jj = j - C_;
      int i = jj >> 3, kk = jj & 7;
      v = spline_w[((size_t)o * C_ + i) * 8 + kk] * spline_s[(size_t)o * C_ + i];
    }
    bpackb[(size_t)o * KTOT_ + j] = f2bf(v);
  }
}

// ---------------- bias precompute ----------------
__device__ __forceinline__ float bilerp7(const float* __restrict__ Bsrc, int y, int x) {
  float sy = y * 0.25f - 0.375f;
  float sx = x * 0.25f - 0.375f;
  float fy0 = floorf(sy), fx0 = floorf(sx);
  int y0 = (int)fy0, x0 = (int)fx0;
  float fy = sy - fy0, fx = sx - fx0;
  int y0c = min(6, max(0, y0)), y1c = min(6, max(0, y0 + 1));
  int x0c = min(6, max(0, x0)), x1c = min(6, max(0, x0 + 1));
  float v00 = Bsrc[y0c * 7 + x0c], v01 = Bsrc[y0c * 7 + x1c];
  float v10 = Bsrc[y1c * 7 + x0c], v11 = Bsrc[y1c * 7 + x1c];
  return (1.f - fy) * ((1.f - fx) * v00 + fx * v01)
       + fy * ((1.f - fx) * v10 + fx * v11);
}

__global__ __launch_bounds__(256) void bias_kernel(
    const float* __restrict__ an_bias, const float* __restrict__ na_bias,
    const float* __restrict__ ah_bias, const float* __restrict__ aw_bias,
    const float* __restrict__ ha_bias, const float* __restrict__ wa_bias,
    float* __restrict__ abias, float* __restrict__ qbias) {
  int idx = blockIdx.x * 256 + threadIdx.x;
  if (idx >= HEADS_ * AGENT_ * N_) return;
  int n = idx % N_;
  int ha = idx / N_;
  int h = ha / AGENT_, a = ha % AGENT_;
  int y = n / W_, x = n % W_;
  float pb1 = bilerp7(an_bias + (size_t)ha * 49, y, x);
  float pb2 = ah_bias[ha * H_ + y] + aw_bias[ha * W_ + x];
  abias[(size_t)ha * N_ + n] = pb1 + pb2;
  float ab1 = bilerp7(na_bias + (size_t)ha * 49, y, x);
  float ab2 = ha_bias[(h * H_ + y) * AGENT_ + a] + wa_bias[(h * W_ + x) * AGENT_ + a];
  qbias[((size_t)h * N_ + n) * AGENT_ + a] = ab1 + ab2;
}

// ---------------- MFMA GEMM: qkv  (A[M][576] bf16, Bt[1728][576] bf16 -> bf16) ----
__global__ __launch_bounds__(256) void mfma_qkv_kernel(
    const ushort_t* __restrict__ A, const ushort_t* __restrict__ Bt,
    ushort_t* __restrict__ out) {
  __shared__ ushort_t Asl[128 * 32];
  __shared__ ushort_t Bsl[192 * 32];
  const int tid = threadIdx.x;
  const int lane = tid & 63, wid = tid >> 6;
  const int wm = wid >> 1, wn = wid & 1;
  const int m0 = blockIdx.y * 128, n0 = blockIdx.x * 192;
  const int l16 = lane & 15, lq = lane >> 4;

  const int rA0 = tid >> 2, cA0 = tid & 3;
  const int rA1 = (tid + 256) >> 2, cA1 = (tid + 256) & 3;
  int rB[3], cB[3];
  #pragma unroll
  for (int u = 0; u < 3; ++u) { int it = tid + u * 256; rB[u] = it >> 2; cB[u] = it & 3; }

  f32x4 acc[4][6] = {};
  u16x8 ar0, ar1, br[3];

  // prefetch k0 = 0
  ar0 = *(const u16x8*)(A + (size_t)(m0 + rA0) * C_ + cA0 * 8);
  ar1 = *(const u16x8*)(A + (size_t)(m0 + rA1) * C_ + cA1 * 8);
  #pragma unroll
  for (int u = 0; u < 3; ++u)
    br[u] = *(const u16x8*)(Bt + (size_t)(n0 + rB[u]) * C_ + cB[u] * 8);

  for (int k0 = 0; k0 < C_; k0 += 32) {
    __syncthreads();
    *(u16x8*)&Asl[tid * 8] = ar0;
    *(u16x8*)&Asl[(tid + 256) * 8] = ar1;
    #pragma unroll
    for (int u = 0; u < 3; ++u) *(u16x8*)&Bsl[(tid + u * 256) * 8] = br[u];
    __syncthreads();
    int kn = k0 + 32;
    if (kn < C_) {
      ar0 = *(const u16x8*)(A + (size_t)(m0 + rA0) * C_ + kn + cA0 * 8);
      ar1 = *(const u16x8*)(A + (size_t)(m0 + rA1) * C_ + kn + cA1 * 8);
      #pragma unroll
      for (int u = 0; u < 3; ++u)
        br[u] = *(const u16x8*)(Bt + (size_t)(n0 + rB[u]) * C_ + kn + cB[u] * 8);
    }
    bf16x8 af[4], bfr[6];
    #pragma unroll
    for (int fm = 0; fm < 4; ++fm)
      af[fm] = *(const bf16x8*)&Asl[(wm * 64 + fm * 16 + l16) * 32 + lq * 8];
    #pragma unroll
    for (int fn = 0; fn < 6; ++fn)
      bfr[fn] = *(const bf16x8*)&Bsl[(wn * 96 + fn * 16 + l16) * 32 + lq * 8];
    #pragma unroll
    for (int fm = 0; fm < 4; ++fm)
      #pragma unroll
      for (int fn = 0; fn < 6; ++fn)
        acc[fm][fn] = __builtin_amdgcn_mfma_f32_16x16x32_bf16(
            af[fm], bfr[fn], acc[fm][fn], 0, 0, 0);
  }
  #pragma unroll
  for (int fm = 0; fm < 4; ++fm) {
    #pragma unroll
    for (int fn = 0; fn < 6; ++fn) {
      int col = n0 + wn * 96 + fn * 16 + l16;
      #pragma unroll
      for (int r = 0; r < 4; ++r) {
        int row = m0 + wm * 64 + fm * 16 + lq * 4 + r;
        out[(size_t)row * QKVW_ + col] = f2bf(acc[fm][fn][r]);
      }
    }
  }
}

// ---------------- KAN MFMA GEMM with on-the-fly A ----------------
__device__ __forceinline__ u16x8 bases8(float xv) {
  float s = (xv + 2.2f) * 2.5f;
  float tc = floorf(s);
  int t = (int)tc;
  float u = s - tc;
  float u2 = u * u, u3 = u2 * u, um = 1.f - u;
  float p0 = u3 * (1.f / 6.f);
  float p1 = (-3.f * u3 + 3.f * u2 + 3.f * u + 1.f) * (1.f / 6.f);
  float p2 = (3.f * u3 - 6.f * u2 + 4.f) * (1.f / 6.f);
  float p3 = um * um * um * (1.f / 6.f);
  bool inr = (t >= 0) && (t <= 10);
  u16x8 o;
  #pragma unroll
  for (int j = 0; j < 8; ++j) {
    float r = 0.f;
    r = (j == t - 3) ? p3 : r;
    r = (j == t - 2) ? p2 : r;
    r = (j == t - 1) ? p1 : r;
    r = (j == t)     ? p0 : r;
    o[j] = f2bf(inr ? r : 0.f);
  }
  return o;
}

__device__ __forceinline__ u16x8 silu8(const float* xv) {
  u16x8 o;
  #pragma unroll
  for (int e = 0; e < 8; ++e) o[e] = f2bf(xv[e] / (1.f + __expf(-xv[e])));
  return o;
}

__global__ __launch_bounds__(256) void kan_mfma_kernel(
    const float* __restrict__ xf, const ushort_t* __restrict__ Bt,
    float* __restrict__ out) {
  __shared__ ushort_t Asl[128 * 32];
  __shared__ ushort_t Bsl[192 * 32];
  const int tid = threadIdx.x;
  const int lane = tid & 63, wid = tid >> 6;
  const int wm = wid >> 1, wn = wid & 1;
  const int m0 = blockIdx.y * 128, n0 = blockIdx.x * 192;
  const int l16 = lane & 15, lq = lane >> 4;

  const int rA0 = tid >> 2, cA0 = tid & 3;
  const int rA1 = (tid + 256) >> 2, cA1 = (tid + 256) & 3;
  const float* xfr0 = xf + (size_t)(m0 + rA0) * C_;
  const float* xfr1 = xf + (size_t)(m0 + rA1) * C_;
  int rB[3], cB[3];
  #pragma unroll
  for (int u = 0; u < 3; ++u) { int it = tid + u * 256; rB[u] = it >> 2; cB[u] = it & 3; }

  f32x4 acc[4][6] = {};
  float xv0[8], xv1[8];
  u16x8 br[3];

  // prefetch k0 = 0 (silu region)
  {
    f32x4 a = *(const f32x4*)(xfr0 + cA0 * 8);
    f32x4 b = *(const f32x4*)(xfr0 + cA0 * 8 + 4);
    xv0[0]=a[0]; xv0[1]=a[1]; xv0[2]=a[2]; xv0[3]=a[3];
    xv0[4]=b[0]; xv0[5]=b[1]; xv0[6]=b[2]; xv0[7]=b[3];
    f32x4 c = *(const f32x4*)(xfr1 + cA1 * 8);
    f32x4 d = *(const f32x4*)(xfr1 + cA1 * 8 + 4);
    xv1[0]=c[0]; xv1[1]=c[1]; xv1[2]=c[2]; xv1[3]=c[3];
    xv1[4]=d[0]; xv1[5]=d[1]; xv1[6]=d[2]; xv1[7]=d[3];
    #pragma unroll
    for (int u = 0; u < 3; ++u)
      br[u] = *(const u16x8*)(Bt + (size_t)(n0 + rB[u]) * KTOT_ + cB[u] * 8);
  }

  for (int k0 = 0; k0 < KTOT_; k0 += 32) {
    u16x8 av0, av1;
    if (k0 < C_) { av0 = silu8(xv0); av1 = silu8(xv1); }
    else         { av0 = bases8(xv0[0]); av1 = bases8(xv1[0]); }
    __syncthreads();
    *(u16x8*)&Asl[tid * 8] = av0;
    *(u16x8*)&Asl[(tid + 256) * 8] = av1;
    #pragma unroll
    for (int u = 0; u < 3; ++u) *(u16x8*)&Bsl[(tid + u * 256) * 8] = br[u];
    __syncthreads();
    int kn = k0 + 32;
    if (kn < KTOT_) {
      if (kn < C_) {
        f32x4 a = *(const f32x4*)(xfr0 + kn + cA0 * 8);
        f32x4 b = *(const f32x4*)(xfr0 + kn + cA0 * 8 + 4);
        xv0[0]=a[0]; xv0[1]=a[1]; xv0[2]=a[2]; xv0[3]=a[3];
        xv0[4]=b[0]; xv0[5]=b[1]; xv0[6]=b[2]; xv0[7]=b[3];
        f32x4 c = *(const f32x4*)(xfr1 + kn + cA1 * 8);
        f32x4 d = *(const f32x4*)(xfr1 + kn + cA1 * 8 + 4);
        xv1[0]=c[0]; xv1[1]=c[1]; xv1[2]=c[2]; xv1[3]=c[3];
        xv1[4]=d[0]; xv1[5]=d[1]; xv1[6]=d[2]; xv1[7]=d[3];
      } else {
        int i0 = (kn - C_) >> 3;
        xv0[0] = xfr0[i0 + cA0];
        xv1[0] = xfr1[i0 + cA1];
      }
      #pragma unroll
      for (int u = 0; u < 3; ++u)
        br[u] = *(const u16x8*)(Bt + (size_t)(n0 + rB[u]) * KTOT_ + kn + cB[u] * 8);
    }
    bf16x8 af[4], bfr[6];
    #pragma unroll
    for (int fm = 0; fm < 4; ++fm)
      af[fm] = *(const bf16x8*)&Asl[(wm * 64 + fm * 16 + l16) * 32 + lq * 8];
    #pragma unroll
    for (int fn = 0; fn < 6; ++fn)
      bfr[fn] = *(const bf16x8*)&Bsl[(wn * 96 + fn * 16 + l16) * 32 + lq * 8];
    #pragma unroll
    for (int fm = 0; fm < 4; ++fm)
      #pragma unroll
      for (int fn = 0; fn < 6; ++fn)
        acc[fm][fn] = __builtin_amdgcn_mfma_f32_16x16x32_bf16(
            af[fm], bfr[fn], acc[fm][fn], 0, 0, 0);
  }
  #pragma unroll
  for (int fm = 0; fm < 4; ++fm) {
    #pragma unroll
    for (int fn = 0; fn < 6; ++fn) {
      int col = n0 + wn * 96 + fn * 16 + l16;
      #pragma unroll
      for (int r = 0; r < 4; ++r) {
        int row = m0 + wm * 64 + fm * 16 + lq * 4 + r;
        out[(size_t)row * C_ + col] = acc[fm][fn][r];
      }
    }
  }
}

// ---------------- agent pooling (reads bf16 q) ----------------
__global__ __launch_bounds__(576) void agent_pool_kernel(
    const ushort_t* __restrict__ qkvb, float* __restrict__ agent) {
  int ba = blockIdx.x;
  int b = ba / AGENT_, a = ba % AGENT_;
  int ay = a / 7, ax = a % 7;
  int ch = threadIdx.x;
  float s = 0.f;
  #pragma unroll
  for (int i2 = 0; i2 < 4; ++i2)
    #pragma unroll
    for (int i4 = 0; i4 < 4; ++i4)
      s += bf2f(qkvb[((size_t)b * N_ + (ay * 4 + i2) * W_ + (ax * 4 + i4)) * QKVW_ + ch]);
  agent[(size_t)ba * C_ + ch] = s * 0.0625f;
}

// ---------------- agent attention ----------------
__global__ __launch_bounds__(256) void agent_attn_kernel(
    const float* __restrict__ agent, const ushort_t* __restrict__ qkvb,
    const float* __restrict__ abias, float* __restrict__ agent_v) {
  __shared__ float ah_s[HD_];
  __shared__ float p_s[N_];
  __shared__ float red[256];
  __shared__ float pv_s[216];
  const int tid = threadIdx.x;
  const int bh = blockIdx.x / AGENT_, a = blockIdx.x % AGENT_;
  const int b = bh >> 3, h = bh & 7;
  if (tid < HD_) ah_s[tid] = agent[((size_t)b * AGENT_ + a) * C_ + h * HD_ + tid];
  __syncthreads();
  float lmax = -1e30f;
  for (int n = tid; n < N_; n += 256) {
    const ushort_t* kp = qkvb + ((size_t)b * N_ + n) * QKVW_ + C_ + h * HD_;
    float dot = 0.f;
    #pragma unroll
    for (int d8 = 0; d8 < 9; ++d8) {
      u16x8 k8 = *(const u16x8*)(kp + d8 * 8);
      #pragma unroll
      for (int e = 0; e < 8; ++e) dot += ah_s[d8 * 8 + e] * bf2f(k8[e]);
    }
    float lg = dot * SCALE_ + abias[((size_t)h * AGENT_ + a) * N_ + n];
    p_s[n] = lg;
    lmax = fmaxf(lmax, lg);
  }
  red[tid] = lmax;
  __syncthreads();
  for (int s2 = 128; s2 > 0; s2 >>= 1) {
    if (tid < s2) red[tid] = fmaxf(red[tid], red[tid + s2]);
    __syncthreads();
  }
  float mx = red[0];
  __syncthreads();
  float lsum = 0.f;
  for (int n = tid; n < N_; n += 256) {
    float e = expf(p_s[n] - mx);
    p_s[n] = e;
    lsum += e;
  }
  red[tid] = lsum;
  __syncthreads();
  for (int s2 = 128; s2 > 0; s2 >>= 1) {
    if (tid < s2) red[tid] += red[tid + s2];
    __syncthreads();
  }
  float inv = 1.f / red[0];
  if (tid < 216) {
    int d = tid % HD_, seg = tid / HD_;
    float acc2 = 0.f;
    for (int n = seg; n < N_; n += 3)
      acc2 += p_s[n] * bf2f(qkvb[((size_t)b * N_ + n) * QKVW_ + 2 * C_ + h * HD_ + d]);
    pv_s[tid] = acc2;
  }
  __syncthreads();
  if (tid < HD_) {
    float r = (pv_s[tid] + pv_s[72 + tid] + pv_s[144 + tid]) * inv;
    agent_v[(size_t)blockIdx.x * HD_ + tid] = r;
  }
}

// ---------------- q attention ----------------
__global__ __launch_bounds__(256) void q_attn_kernel(
    const ushort_t* __restrict__ qkvb, const float* __restrict__ agent,
    const float* __restrict__ agent_v, const float* __restrict__ qbias,
    float* __restrict__ xf) {
  __shared__ float ag_t[HD_ * 52];
  __shared__ float av_t[HD_ * 52];
  const int tid = threadIdx.x;
  const int h = blockIdx.y, b = blockIdx.z;
  for (int t = tid; t < AGENT_ * HD_; t += 256) {
    int a = t / HD_, d = t % HD_;
    ag_t[d * 52 + a] = agent[((size_t)b * AGENT_ + a) * C_ + h * HD_ + d];
    av_t[d * 52 + a] = agent_v[(((size_t)b * HEADS_ + h) * AGENT_ + a) * HD_ + d];
  }
  __syncthreads();
  const int n = blockIdx.x * 256 + tid;
  if (n >= N_) return;
  const ushort_t* qp = qkvb + ((size_t)b * N_ + n) * QKVW_ + h * HD_;
  const float* qb = qbias + ((size_t)h * N_ + n) * AGENT_;
  float lg[AGENT_];
  #pragma unroll
  for (int a = 0; a < AGENT_; ++a) lg[a] = qb[a];
  for (int d = 0; d < HD_; ++d) {
    float qd = bf2f(qp[d]) * SCALE_;
    #pragma unroll
    for (int a = 0; a < AGENT_; ++a) lg[a] += qd * ag_t[d * 52 + a];
  }
  float mx = -1e30f;
  #pragma unroll
  for (int a = 0; a < AGENT_; ++a) mx = fmaxf(mx, lg[a]);
  float s = 0.f;
  #pragma unroll
  for (int a = 0; a < AGENT_; ++a) { lg[a] = expf(lg[a] - mx); s += lg[a]; }
  float inv = 1.f / s;
  #pragma unroll
  for (int a = 0; a < AGENT_; ++a) lg[a] *= inv;
  float* op = xf + ((size_t)b * N_ + n) * C_ + h * HD_;
  for (int d = 0; d < HD_; ++d) {
    float acc = 0.f;
    #pragma unroll
    for (int a = 0; a < AGENT_; ++a) acc += lg[a] * av_t[d * 52 + a];
    op[d] = acc;
  }
}

// ---------------- depthwise conv + BN + ReLU (reads bf16 v) ----------------
__global__ __launch_bounds__(576) void dwc_kernel(
    const ushort_t* __restrict__ qkvb, const float* __restrict__ w,
    const float* __restrict__ bias, const float* __restrict__ gamma,
    const float* __restrict__ beta, const float* __restrict__ mean,
    const float* __restrict__ var, float* __restrict__ xf) {
  const int bn = blockIdx.x;
  const int b = bn / N_, n = bn % N_;
  const int y = n / W_, x = n % W_;
  const int ch = threadIdx.x;
  float acc = 0.f;
  #pragma unroll
  for (int ky = 0; ky < 3; ++ky) {
    int yy = y + ky - 1;
    if (yy < 0 || yy >= H_) continue;
    #pragma unroll
    for (int kx = 0; kx < 3; ++kx) {
      int xx = x + kx - 1;
      if (xx < 0 || xx >= W_) continue;
      acc += w[ch * 9 + ky * 3 + kx]
           * bf2f(qkvb[((size_t)b * N_ + yy * W_ + xx) * QKVW_ + 2 * C_ + ch]);
    }
  }
  float sc = gamma[ch] * rsqrtf(var[ch] + 1e-5f);
  float val = (acc + bias[ch] - mean[ch]) * sc + beta[ch];
  xf[(size_t)bn * C_ + ch] += fmaxf(val, 0.f);
}

extern "C" void kernel_launch(void* const* d_in, const int* in_sizes, int n_in,
                              void* d_out, int out_size, void* d_ws, size_t ws_size,
                              hipStream_t stream) {
  const float* x        = (const float*)d_in[0];
  const float* Wq       = (const float*)d_in[3];
  const float* Wkv      = (const float*)d_in[4];
  const float* an_bias  = (const float*)d_in[5];
  const float* na_bias  = (const float*)d_in[6];
  const float* ah_bias  = (const float*)d_in[7];
  const float* aw_bias  = (const float*)d_in[8];
  const float* ha_bias  = (const float*)d_in[9];
  const float* wa_bias  = (const float*)d_in[10];
  const float* dwc_w    = (const float*)d_in[11];
  const float* dwc_b    = (const float*)d_in[12];
  const float* bn_gamma = (const float*)d_in[13];
  const float* bn_beta  = (const float*)d_in[14];
  const float* bn_mean  = (const float*)d_in[15];
  const float* bn_var   = (const float*)d_in[16];
  const float* base_w   = (const float*)d_in[17];
  const float* spline_w = (const float*)d_in[18];
  const float* spline_s = (const float*)d_in[19];

  char* ws = (char*)d_ws;
  ushort_t* qkvb   = (ushort_t*)(ws + 0);            //  86,704,128 B
  ushort_t* xbf    = (ushort_t*)(ws + 86704128);     //  28,901,376 B
  ushort_t* wbf    = (ushort_t*)(ws + 115605504);    //   1,990,656 B
  ushort_t* bpackb = (ushort_t*)(ws + 117596160);    //   5,971,968 B
  float* agent     = (float*)(ws + 123568128);       //   3,612,672 B
  float* agent_v   = (float*)(ws + 127180800);       //   3,612,672 B
  float* abias     = (float*)(ws + 130793472);       //   1,229,312 B
  float* qbias     = (float*)(ws + 132022784);       //   1,229,312 B
  float* xf        = (float*)(ws + 133252096);       //  57,802,752 B
  float* out       = (float*)d_out;

  convert_x_kernel<<<dim3(2048), dim3(256), 0, stream>>>(x, xbf);
  pack_w_kernel<<<dim3(1024), dim3(256), 0, stream>>>(Wq, Wkv, wbf);
  pack_b_kernel<<<dim3(C_), dim3(256), 0, stream>>>(base_w, spline_w, spline_s, bpackb);
  bias_kernel<<<dim3((HEADS_ * AGENT_ * N_ + 255) / 256), dim3(256), 0, stream>>>(
      an_bias, na_bias, ah_bias, aw_bias, ha_bias, wa_bias, abias, qbias);
  mfma_qkv_kernel<<<dim3(9, 196), dim3(256), 0, stream>>>(xbf, wbf, qkvb);
  agent_pool_kernel<<<dim3(B_ * AGENT_), dim3(C_), 0, stream>>>(qkvb, agent);
  agent_attn_kernel<<<dim3(B_ * HEADS_ * AGENT_), dim3(256), 0, stream>>>(
      agent, qkvb, abias, agent_v);
  q_attn_kernel<<<dim3(4, HEADS_, B_), dim3(256), 0, stream>>>(
      qkvb, agent, agent_v, qbias, xf);
  dwc_kernel<<<dim3(M_), dim3(C_), 0, stream>>>(
      qkvb, dwc_w, dwc_b, bn_gamma, bn_beta, bn_mean, bn_var, xf);
  kan_mfma_kernel<<<dim3(3, 196), dim3(256), 0, stream>>>(xf, bpackb, out);
}

// Round 3
// 1081.016 us; speedup vs baseline: 4.4607x; 1.6284x over previous
//
#include <hip/hip_runtime.h>
#include <hip/hip_bf16.h>
#include <math.h>

#define B_ 32
#define N_ 784
#define C_ 576
#define H_ 28
#define W_ 28
#define HEADS_ 8
#define HD_ 72
#define AGENT_ 49
#define M_ (B_ * N_)            // 25088
#define KTOT_ 5184              // 576 silu + 576*8 spline
#define QKVW_ 1728
#define SCALE_ 0.11785113019775793f

typedef unsigned short ushort_t;
typedef __attribute__((ext_vector_type(8))) unsigned short u16x8;
typedef __attribute__((ext_vector_type(8))) __bf16 bf16x8;
typedef __attribute__((ext_vector_type(4))) float f32x4;

__device__ __forceinline__ ushort_t f2bf(float f) {
  union { float f; unsigned u; } v; v.f = f;
  unsigned r = v.u + 0x7fffu + ((v.u >> 16) & 1u);
  return (ushort_t)(r >> 16);
}
__device__ __forceinline__ float bf2f(ushort_t u) {
  union { unsigned u; float f; } v; v.u = ((unsigned)u) << 16;
  return v.f;
}

// ---------------- converts / packs ----------------
__global__ __launch_bounds__(256) void convert_x_kernel(
    const float* __restrict__ x, ushort_t* __restrict__ xbf) {
  const int total8 = M_ * C_ / 8;
  for (int i = blockIdx.x * 256 + threadIdx.x; i < total8; i += gridDim.x * 256) {
    f32x4 a = *(const f32x4*)(x + i * 8);
    f32x4 b = *(const f32x4*)(x + i * 8 + 4);
    u16x8 o;
    o[0]=f2bf(a[0]); o[1]=f2bf(a[1]); o[2]=f2bf(a[2]); o[3]=f2bf(a[3]);
    o[4]=f2bf(b[0]); o[5]=f2bf(b[1]); o[6]=f2bf(b[2]); o[7]=f2bf(b[3]);
    *(u16x8*)(xbf + i * 8) = o;
  }
}

__global__ __launch_bounds__(256) void pack_w_kernel(
    const float* __restrict__ Wq, const float* __restrict__ Wkv,
    ushort_t* __restrict__ wbf) {
  int total = QKVW_ * C_;
  for (int i = blockIdx.x * 256 + threadIdx.x; i < total; i += gridDim.x * 256) {
    int j = i / C_, k = i % C_;
    float v = (j < C_) ? Wq[(size_t)j * C_ + k] : Wkv[(size_t)(j - C_) * C_ + k];
    wbf[i] = f2bf(v);
  }
}

__global__ __launch_bounds__(256) void pack_b_kernel(
    const float* __restrict__ base_w, const float* __restrict__ spline_w,
    const float* __restrict__ spline_s, ushort_t* __restrict__ bpackb) {
  int o = blockIdx.x;
  for (int j = threadIdx.x; j < KTOT_; j += 256) {
    float v;
    if (j < C_) {
      v = base_w[(size_t)o * C_ + j];
    } else {
      int jj = j - C_;
      int i = jj >> 3, kk = jj & 7;
      v = spline_w[((size_t)o * C_ + i) * 8 + kk] * spline_s[(size_t)o * C_ + i];
    }
    bpackb[(size_t)o * KTOT_ + j] = f2bf(v);
  }
}

// ---------------- bias precompute ----------------
__device__ __forceinline__ float bilerp7(const float* __restrict__ Bsrc, int y, int x) {
  float sy = y * 0.25f - 0.375f;
  float sx = x * 0.25f - 0.375f;
  float fy0 = floorf(sy), fx0 = floorf(sx);
  int y0 = (int)fy0, x0 = (int)fx0;
  float fy = sy - fy0, fx = sx - fx0;
  int y0c = min(6, max(0, y0)), y1c = min(6, max(0, y0 + 1));
  int x0c = min(6, max(0, x0)), x1c = min(6, max(0, x0 + 1));
  float v00 = Bsrc[y0c * 7 + x0c], v01 = Bsrc[y0c * 7 + x1c];
  float v10 = Bsrc[y1c * 7 + x0c], v11 = Bsrc[y1c * 7 + x1c];
  return (1.f - fy) * ((1.f - fx) * v00 + fx * v01)
       + fy * ((1.f - fx) * v10 + fx * v11);
}

__global__ __launch_bounds__(256) void bias_kernel(
    const float* __restrict__ an_bias, const float* __restrict__ na_bias,
    const float* __restrict__ ah_bias, const float* __restrict__ aw_bias,
    const float* __restrict__ ha_bias, const float* __restrict__ wa_bias,
    float* __restrict__ abias, float* __restrict__ qbias) {
  int idx = blockIdx.x * 256 + threadIdx.x;
  if (idx >= HEADS_ * AGENT_ * N_) return;
  int n = idx % N_;
  int ha = idx / N_;
  int h = ha / AGENT_, a = ha % AGENT_;
  int y = n / W_, x = n % W_;
  float pb1 = bilerp7(an_bias + (size_t)ha * 49, y, x);
  float pb2 = ah_bias[ha * H_ + y] + aw_bias[ha * W_ + x];
  abias[(size_t)ha * N_ + n] = pb1 + pb2;
  float ab1 = bilerp7(na_bias + (size_t)ha * 49, y, x);
  float ab2 = ha_bias[(h * H_ + y) * AGENT_ + a] + wa_bias[(h * W_ + x) * AGENT_ + a];
  qbias[((size_t)h * N_ + n) * AGENT_ + a] = ab1 + ab2;
}

// ---------------- MFMA GEMM: qkv ----------------
__global__ __launch_bounds__(256) void mfma_qkv_kernel(
    const ushort_t* __restrict__ A, const ushort_t* __restrict__ Bt,
    ushort_t* __restrict__ out) {
  __shared__ ushort_t Asl[128 * 32];
  __shared__ ushort_t Bsl[192 * 32];
  const int tid = threadIdx.x;
  const int lane = tid & 63, wid = tid >> 6;
  const int wm = wid >> 1, wn = wid & 1;
  const int m0 = blockIdx.y * 128, n0 = blockIdx.x * 192;
  const int l16 = lane & 15, lq = lane >> 4;

  const int rA0 = tid >> 2, cA0 = tid & 3;
  const int rA1 = (tid + 256) >> 2, cA1 = (tid + 256) & 3;
  int rB[3], cB[3];
  #pragma unroll
  for (int u = 0; u < 3; ++u) { int it = tid + u * 256; rB[u] = it >> 2; cB[u] = it & 3; }

  f32x4 acc[4][6] = {};
  u16x8 ar0, ar1, br[3];

  ar0 = *(const u16x8*)(A + (size_t)(m0 + rA0) * C_ + cA0 * 8);
  ar1 = *(const u16x8*)(A + (size_t)(m0 + rA1) * C_ + cA1 * 8);
  #pragma unroll
  for (int u = 0; u < 3; ++u)
    br[u] = *(const u16x8*)(Bt + (size_t)(n0 + rB[u]) * C_ + cB[u] * 8);

  for (int k0 = 0; k0 < C_; k0 += 32) {
    __syncthreads();
    *(u16x8*)&Asl[tid * 8] = ar0;
    *(u16x8*)&Asl[(tid + 256) * 8] = ar1;
    #pragma unroll
    for (int u = 0; u < 3; ++u) *(u16x8*)&Bsl[(tid + u * 256) * 8] = br[u];
    __syncthreads();
    int kn = k0 + 32;
    if (kn < C_) {
      ar0 = *(const u16x8*)(A + (size_t)(m0 + rA0) * C_ + kn + cA0 * 8);
      ar1 = *(const u16x8*)(A + (size_t)(m0 + rA1) * C_ + kn + cA1 * 8);
      #pragma unroll
      for (int u = 0; u < 3; ++u)
        br[u] = *(const u16x8*)(Bt + (size_t)(n0 + rB[u]) * C_ + kn + cB[u] * 8);
    }
    bf16x8 af[4], bfr[6];
    #pragma unroll
    for (int fm = 0; fm < 4; ++fm)
      af[fm] = *(const bf16x8*)&Asl[(wm * 64 + fm * 16 + l16) * 32 + lq * 8];
    #pragma unroll
    for (int fn = 0; fn < 6; ++fn)
      bfr[fn] = *(const bf16x8*)&Bsl[(wn * 96 + fn * 16 + l16) * 32 + lq * 8];
    #pragma unroll
    for (int fm = 0; fm < 4; ++fm)
      #pragma unroll
      for (int fn = 0; fn < 6; ++fn)
        acc[fm][fn] = __builtin_amdgcn_mfma_f32_16x16x32_bf16(
            af[fm], bfr[fn], acc[fm][fn], 0, 0, 0);
  }
  #pragma unroll
  for (int fm = 0; fm < 4; ++fm) {
    #pragma unroll
    for (int fn = 0; fn < 6; ++fn) {
      int col = n0 + wn * 96 + fn * 16 + l16;
      #pragma unroll
      for (int r = 0; r < 4; ++r) {
        int row = m0 + wm * 64 + fm * 16 + lq * 4 + r;
        out[(size_t)row * QKVW_ + col] = f2bf(acc[fm][fn][r]);
      }
    }
  }
}

// ---------------- KAN MFMA GEMM with on-the-fly A ----------------
__device__ __forceinline__ u16x8 bases8(float xv) {
  float s = (xv + 2.2f) * 2.5f;
  float tc = floorf(s);
  int t = (int)tc;
  float u = s - tc;
  float u2 = u * u, u3 = u2 * u, um = 1.f - u;
  float p0 = u3 * (1.f / 6.f);
  float p1 = (-3.f * u3 + 3.f * u2 + 3.f * u + 1.f) * (1.f / 6.f);
  float p2 = (3.f * u3 - 6.f * u2 + 4.f) * (1.f / 6.f);
  float p3 = um * um * um * (1.f / 6.f);
  bool inr = (t >= 0) && (t <= 10);
  u16x8 o;
  #pragma unroll
  for (int j = 0; j < 8; ++j) {
    float r = 0.f;
    r = (j == t - 3) ? p3 : r;
    r = (j == t - 2) ? p2 : r;
    r = (j == t - 1) ? p1 : r;
    r = (j == t)     ? p0 : r;
    o[j] = f2bf(inr ? r : 0.f);
  }
  return o;
}

__device__ __forceinline__ u16x8 silu8(const float* xv) {
  u16x8 o;
  #pragma unroll
  for (int e = 0; e < 8; ++e) o[e] = f2bf(xv[e] / (1.f + __expf(-xv[e])));
  return o;
}

__global__ __launch_bounds__(256) void kan_mfma_kernel(
    const float* __restrict__ xf, const ushort_t* __restrict__ Bt,
    float* __restrict__ out) {
  __shared__ ushort_t Asl[128 * 32];
  __shared__ ushort_t Bsl[192 * 32];
  const int tid = threadIdx.x;
  const int lane = tid & 63, wid = tid >> 6;
  const int wm = wid >> 1, wn = wid & 1;
  const int m0 = blockIdx.y * 128, n0 = blockIdx.x * 192;
  const int l16 = lane & 15, lq = lane >> 4;

  const int rA0 = tid >> 2, cA0 = tid & 3;
  const int rA1 = (tid + 256) >> 2, cA1 = (tid + 256) & 3;
  const float* xfr0 = xf + (size_t)(m0 + rA0) * C_;
  const float* xfr1 = xf + (size_t)(m0 + rA1) * C_;
  int rB[3], cB[3];
  #pragma unroll
  for (int u = 0; u < 3; ++u) { int it = tid + u * 256; rB[u] = it >> 2; cB[u] = it & 3; }

  f32x4 acc[4][6] = {};
  float xv0[8], xv1[8];
  u16x8 br[3];

  {
    f32x4 a = *(const f32x4*)(xfr0 + cA0 * 8);
    f32x4 b = *(const f32x4*)(xfr0 + cA0 * 8 + 4);
    xv0[0]=a[0]; xv0[1]=a[1]; xv0[2]=a[2]; xv0[3]=a[3];
    xv0[4]=b[0]; xv0[5]=b[1]; xv0[6]=b[2]; xv0[7]=b[3];
    f32x4 c = *(const f32x4*)(xfr1 + cA1 * 8);
    f32x4 d = *(const f32x4*)(xfr1 + cA1 * 8 + 4);
    xv1[0]=c[0]; xv1[1]=c[1]; xv1[2]=c[2]; xv1[3]=c[3];
    xv1[4]=d[0]; xv1[5]=d[1]; xv1[6]=d[2]; xv1[7]=d[3];
    #pragma unroll
    for (int u = 0; u < 3; ++u)
      br[u] = *(const u16x8*)(Bt + (size_t)(n0 + rB[u]) * KTOT_ + cB[u] * 8);
  }

  for (int k0 = 0; k0 < KTOT_; k0 += 32) {
    u16x8 av0, av1;
    if (k0 < C_) { av0 = silu8(xv0); av1 = silu8(xv1); }
    else         { av0 = bases8(xv0[0]); av1 = bases8(xv1[0]); }
    __syncthreads();
    *(u16x8*)&Asl[tid * 8] = av0;
    *(u16x8*)&Asl[(tid + 256) * 8] = av1;
    #pragma unroll
    for (int u = 0; u < 3; ++u) *(u16x8*)&Bsl[(tid + u * 256) * 8] = br[u];
    __syncthreads();
    int kn = k0 + 32;
    if (kn < KTOT_) {
      if (kn < C_) {
        f32x4 a = *(const f32x4*)(xfr0 + kn + cA0 * 8);
        f32x4 b = *(const f32x4*)(xfr0 + kn + cA0 * 8 + 4);
        xv0[0]=a[0]; xv0[1]=a[1]; xv0[2]=a[2]; xv0[3]=a[3];
        xv0[4]=b[0]; xv0[5]=b[1]; xv0[6]=b[2]; xv0[7]=b[3];
        f32x4 c = *(const f32x4*)(xfr1 + kn + cA1 * 8);
        f32x4 d = *(const f32x4*)(xfr1 + kn + cA1 * 8 + 4);
        xv1[0]=c[0]; xv1[1]=c[1]; xv1[2]=c[2]; xv1[3]=c[3];
        xv1[4]=d[0]; xv1[5]=d[1]; xv1[6]=d[2]; xv1[7]=d[3];
      } else {
        int i0 = (kn - C_) >> 3;
        xv0[0] = xfr0[i0 + cA0];
        xv1[0] = xfr1[i0 + cA1];
      }
      #pragma unroll
      for (int u = 0; u < 3; ++u)
        br[u] = *(const u16x8*)(Bt + (size_t)(n0 + rB[u]) * KTOT_ + kn + cB[u] * 8);
    }
    bf16x8 af[4], bfr[6];
    #pragma unroll
    for (int fm = 0; fm < 4; ++fm)
      af[fm] = *(const bf16x8*)&Asl[(wm * 64 + fm * 16 + l16) * 32 + lq * 8];
    #pragma unroll
    for (int fn = 0; fn < 6; ++fn)
      bfr[fn] = *(const bf16x8*)&Bsl[(wn * 96 + fn * 16 + l16) * 32 + lq * 8];
    #pragma unroll
    for (int fm = 0; fm < 4; ++fm)
      #pragma unroll
      for (int fn = 0; fn < 6; ++fn)
        acc[fm][fn] = __builtin_amdgcn_mfma_f32_16x16x32_bf16(
            af[fm], bfr[fn], acc[fm][fn], 0, 0, 0);
  }
  #pragma unroll
  for (int fm = 0; fm < 4; ++fm) {
    #pragma unroll
    for (int fn = 0; fn < 6; ++fn) {
      int col = n0 + wn * 96 + fn * 16 + l16;
      #pragma unroll
      for (int r = 0; r < 4; ++r) {
        int row = m0 + wm * 64 + fm * 16 + lq * 4 + r;
        out[(size_t)row * C_ + col] = acc[fm][fn][r];
      }
    }
  }
}

// ---------------- agent pooling ----------------
__global__ __launch_bounds__(576) void agent_pool_kernel(
    const ushort_t* __restrict__ qkvb, float* __restrict__ agent) {
  int ba = blockIdx.x;
  int b = ba / AGENT_, a = ba % AGENT_;
  int ay = a / 7, ax = a % 7;
  int ch = threadIdx.x;
  float s = 0.f;
  #pragma unroll
  for (int i2 = 0; i2 < 4; ++i2)
    #pragma unroll
    for (int i4 = 0; i4 < 4; ++i4)
      s += bf2f(qkvb[((size_t)b * N_ + (ay * 4 + i2) * W_ + (ax * 4 + i4)) * QKVW_ + ch]);
  agent[(size_t)ba * C_ + ch] = s * 0.0625f;
}

// ---------------- agent attention v2: one block per (b,h,half) ----------------
// Phase 1: S[a][n] = scale*A.K + bias  (K row in regs, A broadcast from LDS)
// Phase 2: wave-parallel softmax over n
// Phase 3: PV with V staged in 128-row LDS chunks, thread = (a, d-chunk)
__global__ __launch_bounds__(256) void agent_attn2_kernel(
    const float* __restrict__ agent, const ushort_t* __restrict__ qkvb,
    const float* __restrict__ abias, float* __restrict__ agent_v) {
  __shared__ float S_s[25 * N_];          // 78.4 KB
  __shared__ ushort_t A_s[25 * HD_];      // 3.6 KB
  __shared__ ushort_t VB[128 * HD_];      // 18.4 KB
  __shared__ float inv_s[25];
  const int tid = threadIdx.x;
  const int half = blockIdx.x, h = blockIdx.y, b = blockIdx.z;
  const int a0 = half * 25;
  const int na = half ? 24 : 25;

  // load A (agents) as bf16
  for (int t = tid; t < na * HD_; t += 256) {
    int a = t / HD_, d = t % HD_;
    A_s[a * HD_ + d] = f2bf(agent[((size_t)b * AGENT_ + a0 + a) * C_ + h * HD_ + d]);
  }
  __syncthreads();

  // phase 1
  for (int n = tid; n < N_; n += 256) {
    const ushort_t* kp = qkvb + ((size_t)b * N_ + n) * QKVW_ + C_ + h * HD_;
    u16x8 kreg[9];
    #pragma unroll
    for (int d8 = 0; d8 < 9; ++d8) kreg[d8] = *(const u16x8*)(kp + d8 * 8);
    float acc[25];
    #pragma unroll
    for (int a = 0; a < 25; ++a) acc[a] = 0.f;
    #pragma unroll
    for (int d8 = 0; d8 < 9; ++d8) {
      float kf[8];
      #pragma unroll
      for (int e = 0; e < 8; ++e) kf[e] = bf2f(kreg[d8][e]);
      for (int a = 0; a < na; ++a) {
        u16x8 a8 = *(const u16x8*)&A_s[a * HD_ + d8 * 8];   // wave-uniform broadcast
        #pragma unroll
        for (int e = 0; e < 8; ++e) acc[a] += bf2f(a8[e]) * kf[e];
      }
    }
    const float* bp = abias + ((size_t)h * AGENT_ + a0) * N_ + n;
    for (int a = 0; a < na; ++a)
      S_s[a * N_ + n] = acc[a] * SCALE_ + bp[(size_t)a * N_];
  }
  __syncthreads();

  // phase 2: softmax over n per row a
  {
    const int w = tid >> 6, lane = tid & 63;
    for (int a = w; a < na; a += 4) {
      float m = -1e30f;
      for (int n = lane; n < N_; n += 64) m = fmaxf(m, S_s[a * N_ + n]);
      #pragma unroll
      for (int off = 32; off; off >>= 1) m = fmaxf(m, __shfl_xor(m, off));
      float s = 0.f;
      for (int n = lane; n < N_; n += 64) {
        float e = __expf(S_s[a * N_ + n] - m);
        S_s[a * N_ + n] = e;
        s += e;
      }
      #pragma unroll
      for (int off = 32; off; off >>= 1) s += __shfl_xor(s, off);
      if (lane == 0) inv_s[a] = 1.f / s;
    }
  }

  // phase 3: PV
  const int a_loc = tid / 9, dc = tid % 9;
  const bool act = (tid < 225) && (a_loc < na);
  float acc8[8] = {};
  for (int c0 = 0; c0 < N_; c0 += 128) {
    int cn = min(128, N_ - c0);
    __syncthreads();
    for (int idx = tid; idx < cn * 9; idx += 256) {
      int r = idx / 9, ch = idx % 9;
      *(u16x8*)&VB[(r * 9 + ch) * 8] =
          *(const u16x8*)(qkvb + ((size_t)b * N_ + c0 + r) * QKVW_ + 2 * C_ + h * HD_ + ch * 8);
    }
    __syncthreads();
    if (act) {
      for (int r = 0; r < cn; ++r) {
        float p = S_s[a_loc * N_ + c0 + r];
        u16x8 v8 = *(const u16x8*)&VB[(r * 9 + dc) * 8];
        #pragma unroll
        for (int e = 0; e < 8; ++e) acc8[e] += p * bf2f(v8[e]);
      }
    }
  }
  if (act) {
    float inv = inv_s[a_loc];
    float* op = agent_v + (((size_t)b * HEADS_ + h) * AGENT_ + a0 + a_loc) * HD_ + dc * 8;
    #pragma unroll
    for (int e = 0; e < 8; ++e) op[e] = acc8[e] * inv;
  }
}

// ---------------- q attention ----------------
__global__ __launch_bounds__(256) void q_attn_kernel(
    const ushort_t* __restrict__ qkvb, const float* __restrict__ agent,
    const float* __restrict__ agent_v, const float* __restrict__ qbias,
    float* __restrict__ xf) {
  __shared__ float ag_t[HD_ * 52];
  __shared__ float av_t[HD_ * 52];
  const int tid = threadIdx.x;
  const int h = blockIdx.y, b = blockIdx.z;
  for (int t = tid; t < AGENT_ * HD_; t += 256) {
    int a = t / HD_, d = t % HD_;
    ag_t[d * 52 + a] = agent[((size_t)b * AGENT_ + a) * C_ + h * HD_ + d];
    av_t[d * 52 + a] = agent_v[(((size_t)b * HEADS_ + h) * AGENT_ + a) * HD_ + d];
  }
  __syncthreads();
  const int n = blockIdx.x * 256 + tid;
  if (n >= N_) return;
  const ushort_t* qp = qkvb + ((size_t)b * N_ + n) * QKVW_ + h * HD_;
  const float* qb = qbias + ((size_t)h * N_ + n) * AGENT_;
  float lg[AGENT_];
  #pragma unroll
  for (int a = 0; a < AGENT_; ++a) lg[a] = qb[a];
  for (int d = 0; d < HD_; ++d) {
    float qd = bf2f(qp[d]) * SCALE_;
    #pragma unroll
    for (int a = 0; a < AGENT_; ++a) lg[a] += qd * ag_t[d * 52 + a];
  }
  float mx = -1e30f;
  #pragma unroll
  for (int a = 0; a < AGENT_; ++a) mx = fmaxf(mx, lg[a]);
  float s = 0.f;
  #pragma unroll
  for (int a = 0; a < AGENT_; ++a) { lg[a] = __expf(lg[a] - mx); s += lg[a]; }
  float inv = 1.f / s;
  #pragma unroll
  for (int a = 0; a < AGENT_; ++a) lg[a] *= inv;
  float* op = xf + ((size_t)b * N_ + n) * C_ + h * HD_;
  for (int d = 0; d < HD_; ++d) {
    float acc = 0.f;
    #pragma unroll
    for (int a = 0; a < AGENT_; ++a) acc += lg[a] * av_t[d * 52 + a];
    op[d] = acc;
  }
}

// ---------------- depthwise conv + BN + ReLU ----------------
__global__ __launch_bounds__(576) void dwc_kernel(
    const ushort_t* __restrict__ qkvb, const float* __restrict__ w,
    const float* __restrict__ bias, const float* __restrict__ gamma,
    const float* __restrict__ beta, const float* __restrict__ mean,
    const float* __restrict__ var, float* __restrict__ xf) {
  const int bn = blockIdx.x;
  const int b = bn / N_, n = bn % N_;
  const int y = n / W_, x = n % W_;
  const int ch = threadIdx.x;
  float acc = 0.f;
  #pragma unroll
  for (int ky = 0; ky < 3; ++ky) {
    int yy = y + ky - 1;
    if (yy < 0 || yy >= H_) continue;
    #pragma unroll
    for (int kx = 0; kx < 3; ++kx) {
      int xx = x + kx - 1;
      if (xx < 0 || xx >= W_) continue;
      acc += w[ch * 9 + ky * 3 + kx]
           * bf2f(qkvb[((size_t)b * N_ + yy * W_ + xx) * QKVW_ + 2 * C_ + ch]);
    }
  }
  float sc = gamma[ch] * rsqrtf(var[ch] + 1e-5f);
  float val = (acc + bias[ch] - mean[ch]) * sc + beta[ch];
  xf[(size_t)bn * C_ + ch] += fmaxf(val, 0.f);
}

extern "C" void kernel_launch(void* const* d_in, const int* in_sizes, int n_in,
                              void* d_out, int out_size, void* d_ws, size_t ws_size,
                              hipStream_t stream) {
  const float* x        = (const float*)d_in[0];
  const float* Wq       = (const float*)d_in[3];
  const float* Wkv      = (const float*)d_in[4];
  const float* an_bias  = (const float*)d_in[5];
  const float* na_bias  = (const float*)d_in[6];
  const float* ah_bias  = (const float*)d_in[7];
  const float* aw_bias  = (const float*)d_in[8];
  const float* ha_bias  = (const float*)d_in[9];
  const float* wa_bias  = (const float*)d_in[10];
  const float* dwc_w    = (const float*)d_in[11];
  const float* dwc_b    = (const float*)d_in[12];
  const float* bn_gamma = (const float*)d_in[13];
  const float* bn_beta  = (const float*)d_in[14];
  const float* bn_mean  = (const float*)d_in[15];
  const float* bn_var   = (const float*)d_in[16];
  const float* base_w   = (const float*)d_in[17];
  const float* spline_w = (const float*)d_in[18];
  const float* spline_s = (const float*)d_in[19];

  char* ws = (char*)d_ws;
  ushort_t* qkvb   = (ushort_t*)(ws + 0);
  ushort_t* xbf    = (ushort_t*)(ws + 86704128);
  ushort_t* wbf    = (ushort_t*)(ws + 115605504);
  ushort_t* bpackb = (ushort_t*)(ws + 117596160);
  float* agent     = (float*)(ws + 123568128);
  float* agent_v   = (float*)(ws + 127180800);
  float* abias     = (float*)(ws + 130793472);
  float* qbias     = (float*)(ws + 132022784);
  float* xf        = (float*)(ws + 133252096);
  float* out       = (float*)d_out;

  convert_x_kernel<<<dim3(2048), dim3(256), 0, stream>>>(x, xbf);
  pack_w_kernel<<<dim3(1024), dim3(256), 0, stream>>>(Wq, Wkv, wbf);
  pack_b_kernel<<<dim3(C_), dim3(256), 0, stream>>>(base_w, spline_w, spline_s, bpackb);
  bias_kernel<<<dim3((HEADS_ * AGENT_ * N_ + 255) / 256), dim3(256), 0, stream>>>(
      an_bias, na_bias, ah_bias, aw_bias, ha_bias, wa_bias, abias, qbias);
  mfma_qkv_kernel<<<dim3(9, 196), dim3(256), 0, stream>>>(xbf, wbf, qkvb);
  agent_pool_kernel<<<dim3(B_ * AGENT_), dim3(C_), 0, stream>>>(qkvb, agent);
  agent_attn2_kernel<<<dim3(2, HEADS_, B_), dim3(256), 0, stream>>>(
      agent, qkvb, abias, agent_v);
  q_attn_kernel<<<dim3(4, HEADS_, B_), dim3(256), 0, stream>>>(
      qkvb, agent, agent_v, qbias, xf);
  dwc_kernel<<<dim3(M_), dim3(C_), 0, stream>>>(
      qkvb, dwc_w, dwc_b, bn_gamma, bn_beta, bn_mean, bn_var, xf);
  kan_mfma_kernel<<<dim3(3, 196), dim3(256), 0, stream>>>(xf, bpackb, out);
}

// Round 4
// 1015.307 us; speedup vs baseline: 4.7494x; 1.0647x over previous
//
#include <hip/hip_runtime.h>
#include <hip/hip_bf16.h>
#include <math.h>

#define B_ 32
#define N_ 784
#define C_ 576
#define H_ 28
#define W_ 28
#define HEADS_ 8
#define HD_ 72
#define AGENT_ 49
#define M_ (B_ * N_)            // 25088
#define KTOT_ 5184              // 576 silu + 576*8 spline
#define QKVW_ 1728
#define SCALE_ 0.11785113019775793f
#define LDA_ 40                 // padded LDS row stride (elems) for BK=32

typedef unsigned short ushort_t;
typedef __attribute__((ext_vector_type(8))) unsigned short u16x8;
typedef __attribute__((ext_vector_type(8))) __bf16 bf16x8;
typedef __attribute__((ext_vector_type(4))) float f32x4;
typedef __attribute__((ext_vector_type(4))) unsigned u32x4;

__device__ __forceinline__ ushort_t f2bf(float f) {
  union { float f; unsigned u; } v; v.f = f;
  unsigned r = v.u + 0x7fffu + ((v.u >> 16) & 1u);
  return (ushort_t)(r >> 16);
}
__device__ __forceinline__ float bf2f(ushort_t u) {
  union { unsigned u; float f; } v; v.u = ((unsigned)u) << 16;
  return v.f;
}
__device__ __forceinline__ unsigned pack2(float lo, float hi) {
  __bf16 a = (__bf16)lo, b = (__bf16)hi;
  unsigned short ua = __builtin_bit_cast(unsigned short, a);
  unsigned short ub = __builtin_bit_cast(unsigned short, b);
  return (unsigned)ua | ((unsigned)ub << 16);
}

// ---------------- converts / packs ----------------
__global__ __launch_bounds__(256) void convert_x_kernel(
    const float* __restrict__ x, ushort_t* __restrict__ xbf) {
  const int total8 = M_ * C_ / 8;
  for (int i = blockIdx.x * 256 + threadIdx.x; i < total8; i += gridDim.x * 256) {
    f32x4 a = *(const f32x4*)(x + i * 8);
    f32x4 b = *(const f32x4*)(x + i * 8 + 4);
    u16x8 o;
    o[0]=f2bf(a[0]); o[1]=f2bf(a[1]); o[2]=f2bf(a[2]); o[3]=f2bf(a[3]);
    o[4]=f2bf(b[0]); o[5]=f2bf(b[1]); o[6]=f2bf(b[2]); o[7]=f2bf(b[3]);
    *(u16x8*)(xbf + i * 8) = o;
  }
}

__global__ __launch_bounds__(256) void pack_w_kernel(
    const float* __restrict__ Wq, const float* __restrict__ Wkv,
    ushort_t* __restrict__ wbf) {
  int total = QKVW_ * C_;
  for (int i = blockIdx.x * 256 + threadIdx.x; i < total; i += gridDim.x * 256) {
    int j = i / C_, k = i % C_;
    float v = (j < C_) ? Wq[(size_t)j * C_ + k] : Wkv[(size_t)(j - C_) * C_ + k];
    wbf[i] = f2bf(v);
  }
}

__global__ __launch_bounds__(256) void pack_b_kernel(
    const float* __restrict__ base_w, const float* __restrict__ spline_w,
    const float* __restrict__ spline_s, ushort_t* __restrict__ bpackb) {
  int o = blockIdx.x;
  for (int j = threadIdx.x; j < KTOT_; j += 256) {
    float v;
    if (j < C_) {
      v = base_w[(size_t)o * C_ + j];
    } else {
      int jj = j - C_;
      int i = jj >> 3, kk = jj & 7;
      v = spline_w[((size_t)o * C_ + i) * 8 + kk] * spline_s[(size_t)o * C_ + i];
    }
    bpackb[(size_t)o * KTOT_ + j] = f2bf(v);
  }
}

// ---------------- bias precompute ----------------
__device__ __forceinline__ float bilerp7(const float* __restrict__ Bsrc, int y, int x) {
  float sy = y * 0.25f - 0.375f;
  float sx = x * 0.25f - 0.375f;
  float fy0 = floorf(sy), fx0 = floorf(sx);
  int y0 = (int)fy0, x0 = (int)fx0;
  float fy = sy - fy0, fx = sx - fx0;
  int y0c = min(6, max(0, y0)), y1c = min(6, max(0, y0 + 1));
  int x0c = min(6, max(0, x0)), x1c = min(6, max(0, x0 + 1));
  float v00 = Bsrc[y0c * 7 + x0c], v01 = Bsrc[y0c * 7 + x1c];
  float v10 = Bsrc[y1c * 7 + x0c], v11 = Bsrc[y1c * 7 + x1c];
  return (1.f - fy) * ((1.f - fx) * v00 + fx * v01)
       + fy * ((1.f - fx) * v10 + fx * v11);
}

__global__ __launch_bounds__(256) void bias_kernel(
    const float* __restrict__ an_bias, const float* __restrict__ na_bias,
    const float* __restrict__ ah_bias, const float* __restrict__ aw_bias,
    const float* __restrict__ ha_bias, const float* __restrict__ wa_bias,
    float* __restrict__ abias, float* __restrict__ qbias) {
  int idx = blockIdx.x * 256 + threadIdx.x;
  if (idx >= HEADS_ * AGENT_ * N_) return;
  int n = idx % N_;
  int ha = idx / N_;
  int h = ha / AGENT_, a = ha % AGENT_;
  int y = n / W_, x = n % W_;
  float pb1 = bilerp7(an_bias + (size_t)ha * 49, y, x);
  float pb2 = ah_bias[ha * H_ + y] + aw_bias[ha * W_ + x];
  abias[(size_t)ha * N_ + n] = pb1 + pb2;
  float ab1 = bilerp7(na_bias + (size_t)ha * 49, y, x);
  float ab2 = ha_bias[(h * H_ + y) * AGENT_ + a] + wa_bias[(h * W_ + x) * AGENT_ + a];
  qbias[((size_t)h * N_ + n) * AGENT_ + a] = ab1 + ab2;
}

// ---------------- MFMA GEMM: qkv (dbuf, single barrier, padded LDS) ----------
__global__ __launch_bounds__(256, 2) void mfma_qkv_kernel(
    const ushort_t* __restrict__ A, const ushort_t* __restrict__ Bt,
    ushort_t* __restrict__ out) {
  __shared__ ushort_t Asl[2][128 * LDA_];
  __shared__ ushort_t Bsl[2][192 * LDA_];
  const int tid = threadIdx.x;
  const int lane = tid & 63, wid = tid >> 6;
  const int wm = wid >> 1, wn = wid & 1;
  const int m0 = blockIdx.y * 128, n0 = blockIdx.x * 192;
  const int l16 = lane & 15, lq = lane >> 4;

  const int rA = tid >> 1, hA = tid & 1;
  int rB[3], cB[3];
  #pragma unroll
  for (int u = 0; u < 3; ++u) { int it = tid + u * 256; rB[u] = it >> 2; cB[u] = it & 3; }

  const ushort_t* arow = A + (size_t)(m0 + rA) * C_ + hA * 16;

  f32x4 acc[4][6] = {};
  u16x8 ar0, ar1, br[3];

  // step 0 load + write buf0
  ar0 = *(const u16x8*)(arow + 0);
  ar1 = *(const u16x8*)(arow + 8);
  #pragma unroll
  for (int u = 0; u < 3; ++u)
    br[u] = *(const u16x8*)(Bt + (size_t)(n0 + rB[u]) * C_ + cB[u] * 8);
  *(u16x8*)&Asl[0][rA * LDA_ + hA * 16] = ar0;
  *(u16x8*)&Asl[0][rA * LDA_ + hA * 16 + 8] = ar1;
  #pragma unroll
  for (int u = 0; u < 3; ++u) *(u16x8*)&Bsl[0][rB[u] * LDA_ + cB[u] * 8] = br[u];
  // step 1 load
  ar0 = *(const u16x8*)(arow + 32);
  ar1 = *(const u16x8*)(arow + 40);
  #pragma unroll
  for (int u = 0; u < 3; ++u)
    br[u] = *(const u16x8*)(Bt + (size_t)(n0 + rB[u]) * C_ + 32 + cB[u] * 8);
  __syncthreads();

  const int NSTEP = C_ / 32;   // 18
  for (int s = 0; s < NSTEP; ++s) {
    const int cur = s & 1;
    bf16x8 af[4], bfr[6];
    #pragma unroll
    for (int fm = 0; fm < 4; ++fm)
      af[fm] = *(const bf16x8*)&Asl[cur][(wm * 64 + fm * 16 + l16) * LDA_ + lq * 8];
    #pragma unroll
    for (int fn = 0; fn < 6; ++fn)
      bfr[fn] = *(const bf16x8*)&Bsl[cur][(wn * 96 + fn * 16 + l16) * LDA_ + lq * 8];
    #pragma unroll
    for (int fm = 0; fm < 4; ++fm)
      #pragma unroll
      for (int fn = 0; fn < 6; ++fn)
        acc[fm][fn] = __builtin_amdgcn_mfma_f32_16x16x32_bf16(
            af[fm], bfr[fn], acc[fm][fn], 0, 0, 0);
    if (s + 1 < NSTEP) {
      const int nxt = cur ^ 1;
      *(u16x8*)&Asl[nxt][rA * LDA_ + hA * 16] = ar0;
      *(u16x8*)&Asl[nxt][rA * LDA_ + hA * 16 + 8] = ar1;
      #pragma unroll
      for (int u = 0; u < 3; ++u) *(u16x8*)&Bsl[nxt][rB[u] * LDA_ + cB[u] * 8] = br[u];
      if (s + 2 < NSTEP) {
        const int kl = (s + 2) * 32;
        ar0 = *(const u16x8*)(arow + kl);
        ar1 = *(const u16x8*)(arow + kl + 8);
        #pragma unroll
        for (int u = 0; u < 3; ++u)
          br[u] = *(const u16x8*)(Bt + (size_t)(n0 + rB[u]) * C_ + kl + cB[u] * 8);
      }
    }
    __syncthreads();
  }
  #pragma unroll
  for (int fm = 0; fm < 4; ++fm) {
    #pragma unroll
    for (int fn = 0; fn < 6; ++fn) {
      int col = n0 + wn * 96 + fn * 16 + l16;
      #pragma unroll
      for (int r = 0; r < 4; ++r) {
        int row = m0 + wm * 64 + fm * 16 + lq * 4 + r;
        out[(size_t)row * QKVW_ + col] = f2bf(acc[fm][fn][r]);
      }
    }
  }
}

// ---------------- KAN A-operand generation (fast) ----------------
__device__ __forceinline__ u32x4 basesPack(float xv) {
  float s = __fmaf_rn(xv, 2.5f, 5.5f);
  float tf = floorf(s);
  int t = (int)tf;
  float u = s - tf;
  float u2 = u * u, u3 = u2 * u, um = 1.f - u;
  float p0 = u3 * (1.f / 6.f);
  float p1 = (-3.f * u3 + 3.f * u2 + 3.f * u + 1.f) * (1.f / 6.f);
  float p2 = (3.f * u3 - 6.f * u2 + 4.f) * (1.f / 6.f);
  float p3 = um * um * um * (1.f / 6.f);
  unsigned lo = pack2(p3, p2);           // p3 in bits 0-15
  unsigned hi = pack2(p1, p0);
  unsigned cm1 = lo << 16;               // d=-1: (0, p3)
  unsigned c1  = (lo >> 16) | (hi << 16);// d= 1: (p2, p1)
  unsigned c3  = hi >> 16;               // d= 3: (p0, 0)
  bool inr = (t >= 0) && (t <= 10);
  u32x4 o;
  #pragma unroll
  for (int j = 0; j < 4; ++j) {
    int d = 3 - t + 2 * j;
    unsigned r = 0u;
    r = (d == -1) ? cm1 : r;
    r = (d == 0)  ? lo  : r;
    r = (d == 1)  ? c1  : r;
    r = (d == 2)  ? hi  : r;
    r = (d == 3)  ? c3  : r;
    o[j] = inr ? r : 0u;
  }
  return o;
}

__device__ __forceinline__ u32x4 siluPack(const float* xv) {
  u32x4 o;
  #pragma unroll
  for (int e = 0; e < 4; ++e) {
    float v0 = xv[2 * e], v1 = xv[2 * e + 1];
    float s0 = v0 / (1.f + __expf(-v0));
    float s1 = v1 / (1.f + __expf(-v1));
    o[e] = pack2(s0, s1);
  }
  return o;
}

// ---------------- KAN MFMA GEMM (dbuf, single barrier, padded LDS) ----------
__global__ __launch_bounds__(256, 2) void kan_mfma_kernel(
    const float* __restrict__ xf, const ushort_t* __restrict__ Bt,
    float* __restrict__ out) {
  __shared__ ushort_t Asl[2][128 * LDA_];
  __shared__ ushort_t Bsl[2][192 * LDA_];
  const int tid = threadIdx.x;
  const int lane = tid & 63, wid = tid >> 6;
  const int wm = wid >> 1, wn = wid & 1;
  const int m0 = blockIdx.y * 128, n0 = blockIdx.x * 192;
  const int l16 = lane & 15, lq = lane >> 4;

  const int rA = tid >> 1, hA = tid & 1;
  int rB[3], cB[3];
  #pragma unroll
  for (int u = 0; u < 3; ++u) { int it = tid + u * 256; rB[u] = it >> 2; cB[u] = it & 3; }

  const float* xfr = xf + (size_t)(m0 + rA) * C_;

  f32x4 acc[4][6] = {};
  float xv[16];
  u16x8 br[3];

  // load step0 (silu region)
  #pragma unroll
  for (int q = 0; q < 4; ++q) {
    f32x4 t4 = *(const f32x4*)(xfr + hA * 16 + q * 4);
    xv[q * 4 + 0] = t4[0]; xv[q * 4 + 1] = t4[1];
    xv[q * 4 + 2] = t4[2]; xv[q * 4 + 3] = t4[3];
  }
  #pragma unroll
  for (int u = 0; u < 3; ++u)
    br[u] = *(const u16x8*)(Bt + (size_t)(n0 + rB[u]) * KTOT_ + cB[u] * 8);
  // gen+write step0
  {
    u32x4 a0 = siluPack(xv), a1 = siluPack(xv + 8);
    *(u32x4*)&Asl[0][rA * LDA_ + hA * 16] = a0;
    *(u32x4*)&Asl[0][rA * LDA_ + hA * 16 + 8] = a1;
    #pragma unroll
    for (int u = 0; u < 3; ++u) *(u16x8*)&Bsl[0][rB[u] * LDA_ + cB[u] * 8] = br[u];
  }
  // load step1
  #pragma unroll
  for (int q = 0; q < 4; ++q) {
    f32x4 t4 = *(const f32x4*)(xfr + 32 + hA * 16 + q * 4);
    xv[q * 4 + 0] = t4[0]; xv[q * 4 + 1] = t4[1];
    xv[q * 4 + 2] = t4[2]; xv[q * 4 + 3] = t4[3];
  }
  #pragma unroll
  for (int u = 0; u < 3; ++u)
    br[u] = *(const u16x8*)(Bt + (size_t)(n0 + rB[u]) * KTOT_ + 32 + cB[u] * 8);
  __syncthreads();

  const int NSTEP = KTOT_ / 32;   // 162
  for (int s = 0; s < NSTEP; ++s) {
    const int cur = s & 1;
    bf16x8 af[4], bfr[6];
    #pragma unroll
    for (int fm = 0; fm < 4; ++fm)
      af[fm] = *(const bf16x8*)&Asl[cur][(wm * 64 + fm * 16 + l16) * LDA_ + lq * 8];
    #pragma unroll
    for (int fn = 0; fn < 6; ++fn)
      bfr[fn] = *(const bf16x8*)&Bsl[cur][(wn * 96 + fn * 16 + l16) * LDA_ + lq * 8];
    #pragma unroll
    for (int fm = 0; fm < 4; ++fm)
      #pragma unroll
      for (int fn = 0; fn < 6; ++fn)
        acc[fm][fn] = __builtin_amdgcn_mfma_f32_16x16x32_bf16(
            af[fm], bfr[fn], acc[fm][fn], 0, 0, 0);
    if (s + 1 < NSTEP) {
      const int nxt = cur ^ 1;
      const int kg = (s + 1) * 32;
      u32x4 a0, a1;
      if (kg < C_) { a0 = siluPack(xv); a1 = siluPack(xv + 8); }
      else         { a0 = basesPack(xv[0]); a1 = basesPack(xv[1]); }
      *(u32x4*)&Asl[nxt][rA * LDA_ + hA * 16] = a0;
      *(u32x4*)&Asl[nxt][rA * LDA_ + hA * 16 + 8] = a1;
      #pragma unroll
      for (int u = 0; u < 3; ++u) *(u16x8*)&Bsl[nxt][rB[u] * LDA_ + cB[u] * 8] = br[u];
      if (s + 2 < NSTEP) {
        const int kl = (s + 2) * 32;
        if (kl < C_) {
          #pragma unroll
          for (int q = 0; q < 4; ++q) {
            f32x4 t4 = *(const f32x4*)(xfr + kl + hA * 16 + q * 4);
            xv[q * 4 + 0] = t4[0]; xv[q * 4 + 1] = t4[1];
            xv[q * 4 + 2] = t4[2]; xv[q * 4 + 3] = t4[3];
          }
        } else {
          int i0 = ((kl - C_) >> 3) + hA * 2;
          xv[0] = xfr[i0];
          xv[1] = xfr[i0 + 1];
        }
        #pragma unroll
        for (int u = 0; u < 3; ++u)
          br[u] = *(const u16x8*)(Bt + (size_t)(n0 + rB[u]) * KTOT_ + kl + cB[u] * 8);
      }
    }
    __syncthreads();
  }
  #pragma unroll
  for (int fm = 0; fm < 4; ++fm) {
    #pragma unroll
    for (int fn = 0; fn < 6; ++fn) {
      int col = n0 + wn * 96 + fn * 16 + l16;
      #pragma unroll
      for (int r = 0; r < 4; ++r) {
        int row = m0 + wm * 64 + fm * 16 + lq * 4 + r;
        out[(size_t)row * C_ + col] = acc[fm][fn][r];
      }
    }
  }
}

// ---------------- agent pooling ----------------
__global__ __launch_bounds__(576) void agent_pool_kernel(
    const ushort_t* __restrict__ qkvb, float* __restrict__ agent) {
  int ba = blockIdx.x;
  int b = ba / AGENT_, a = ba % AGENT_;
  int ay = a / 7, ax = a % 7;
  int ch = threadIdx.x;
  float s = 0.f;
  #pragma unroll
  for (int i2 = 0; i2 < 4; ++i2)
    #pragma unroll
    for (int i4 = 0; i4 < 4; ++i4)
      s += bf2f(qkvb[((size_t)b * N_ + (ay * 4 + i2) * W_ + (ax * 4 + i4)) * QKVW_ + ch]);
  agent[(size_t)ba * C_ + ch] = s * 0.0625f;
}

// ---------------- agent attention (fused, one block per (b,h,half)) --------
__global__ __launch_bounds__(256) void agent_attn2_kernel(
    const float* __restrict__ agent, const ushort_t* __restrict__ qkvb,
    const float* __restrict__ abias, float* __restrict__ agent_v) {
  __shared__ float S_s[25 * N_];
  __shared__ ushort_t A_s[25 * HD_];
  __shared__ ushort_t VB[128 * HD_];
  __shared__ float inv_s[25];
  const int tid = threadIdx.x;
  const int half = blockIdx.x, h = blockIdx.y, b = blockIdx.z;
  const int a0 = half * 25;
  const int na = half ? 24 : 25;

  for (int t = tid; t < na * HD_; t += 256) {
    int a = t / HD_, d = t % HD_;
    A_s[a * HD_ + d] = f2bf(agent[((size_t)b * AGENT_ + a0 + a) * C_ + h * HD_ + d]);
  }
  __syncthreads();

  for (int n = tid; n < N_; n += 256) {
    const ushort_t* kp = qkvb + ((size_t)b * N_ + n) * QKVW_ + C_ + h * HD_;
    u16x8 kreg[9];
    #pragma unroll
    for (int d8 = 0; d8 < 9; ++d8) kreg[d8] = *(const u16x8*)(kp + d8 * 8);
    float acc[25];
    #pragma unroll
    for (int a = 0; a < 25; ++a) acc[a] = 0.f;
    #pragma unroll
    for (int d8 = 0; d8 < 9; ++d8) {
      float kf[8];
      #pragma unroll
      for (int e = 0; e < 8; ++e) kf[e] = bf2f(kreg[d8][e]);
      for (int a = 0; a < na; ++a) {
        u16x8 a8 = *(const u16x8*)&A_s[a * HD_ + d8 * 8];
        #pragma unroll
        for (int e = 0; e < 8; ++e) acc[a] += bf2f(a8[e]) * kf[e];
      }
    }
    const float* bp = abias + ((size_t)h * AGENT_ + a0) * N_ + n;
    for (int a = 0; a < na; ++a)
      S_s[a * N_ + n] = acc[a] * SCALE_ + bp[(size_t)a * N_];
  }
  __syncthreads();

  {
    const int w = tid >> 6, lane = tid & 63;
    for (int a = w; a < na; a += 4) {
      float m = -1e30f;
      for (int n = lane; n < N_; n += 64) m = fmaxf(m, S_s[a * N_ + n]);
      #pragma unroll
      for (int off = 32; off; off >>= 1) m = fmaxf(m, __shfl_xor(m, off));
      float s = 0.f;
      for (int n = lane; n < N_; n += 64) {
        float e = __expf(S_s[a * N_ + n] - m);
        S_s[a * N_ + n] = e;
        s += e;
      }
      #pragma unroll
      for (int off = 32; off; off >>= 1) s += __shfl_xor(s, off);
      if (lane == 0) inv_s[a] = 1.f / s;
    }
  }

  const int a_loc = tid / 9, dc = tid % 9;
  const bool act = (tid < 225) && (a_loc < na);
  float acc8[8] = {};
  for (int c0 = 0; c0 < N_; c0 += 128) {
    int cn = min(128, N_ - c0);
    __syncthreads();
    for (int idx = tid; idx < cn * 9; idx += 256) {
      int r = idx / 9, ch = idx % 9;
      *(u16x8*)&VB[(r * 9 + ch) * 8] =
          *(const u16x8*)(qkvb + ((size_t)b * N_ + c0 + r) * QKVW_ + 2 * C_ + h * HD_ + ch * 8);
    }
    __syncthreads();
    if (act) {
      for (int r = 0; r < cn; ++r) {
        float p = S_s[a_loc * N_ + c0 + r];
        u16x8 v8 = *(const u16x8*)&VB[(r * 9 + dc) * 8];
        #pragma unroll
        for (int e = 0; e < 8; ++e) acc8[e] += p * bf2f(v8[e]);
      }
    }
  }
  if (act) {
    float inv = inv_s[a_loc];
    float* op = agent_v + (((size_t)b * HEADS_ + h) * AGENT_ + a0 + a_loc) * HD_ + dc * 8;
    #pragma unroll
    for (int e = 0; e < 8; ++e) op[e] = acc8[e] * inv;
  }
}

// ---------------- q attention ----------------
__global__ __launch_bounds__(256) void q_attn_kernel(
    const ushort_t* __restrict__ qkvb, const float* __restrict__ agent,
    const float* __restrict__ agent_v, const float* __restrict__ qbias,
    float* __restrict__ xf) {
  __shared__ float ag_t[HD_ * 52];
  __shared__ float av_t[HD_ * 52];
  const int tid = threadIdx.x;
  const int h = blockIdx.y, b = blockIdx.z;
  for (int t = tid; t < AGENT_ * HD_; t += 256) {
    int a = t / HD_, d = t % HD_;
    ag_t[d * 52 + a] = agent[((size_t)b * AGENT_ + a) * C_ + h * HD_ + d];
    av_t[d * 52 + a] = agent_v[(((size_t)b * HEADS_ + h) * AGENT_ + a) * HD_ + d];
  }
  __syncthreads();
  const int n = blockIdx.x * 256 + tid;
  if (n >= N_) return;
  const ushort_t* qp = qkvb + ((size_t)b * N_ + n) * QKVW_ + h * HD_;
  const float* qb = qbias + ((size_t)h * N_ + n) * AGENT_;
  float lg[AGENT_];
  #pragma unroll
  for (int a = 0; a < AGENT_; ++a) lg[a] = qb[a];
  for (int d = 0; d < HD_; ++d) {
    float qd = bf2f(qp[d]) * SCALE_;
    #pragma unroll
    for (int a = 0; a < AGENT_; ++a) lg[a] += qd * ag_t[d * 52 + a];
  }
  float mx = -1e30f;
  #pragma unroll
  for (int a = 0; a < AGENT_; ++a) mx = fmaxf(mx, lg[a]);
  float s = 0.f;
  #pragma unroll
  for (int a = 0; a < AGENT_; ++a) { lg[a] = __expf(lg[a] - mx); s += lg[a]; }
  float inv = 1.f / s;
  #pragma unroll
  for (int a = 0; a < AGENT_; ++a) lg[a] *= inv;
  float* op = xf + ((size_t)b * N_ + n) * C_ + h * HD_;
  for (int d = 0; d < HD_; ++d) {
    float acc = 0.f;
    #pragma unroll
    for (int a = 0; a < AGENT_; ++a) acc += lg[a] * av_t[d * 52 + a];
    op[d] = acc;
  }
}

// ---------------- depthwise conv + BN + ReLU (2ch/thread) ----------------
__global__ __launch_bounds__(288) void dwc_kernel(
    const ushort_t* __restrict__ qkvb, const float* __restrict__ w,
    const float* __restrict__ bias, const float* __restrict__ gamma,
    const float* __restrict__ beta, const float* __restrict__ mean,
    const float* __restrict__ var, float* __restrict__ xf) {
  const int bn = blockIdx.x;
  const int b = bn / N_, n = bn % N_;
  const int y = n / W_, x = n % W_;
  const int c0 = threadIdx.x * 2;
  float a0 = 0.f, a1 = 0.f;
  #pragma unroll
  for (int ky = 0; ky < 3; ++ky) {
    int yy = y + ky - 1;
    if (yy < 0 || yy >= H_) continue;
    #pragma unroll
    for (int kx = 0; kx < 3; ++kx) {
      int xx = x + kx - 1;
      if (xx < 0 || xx >= W_) continue;
      unsigned v = *(const unsigned*)(qkvb + ((size_t)b * N_ + yy * W_ + xx) * QKVW_ + 2 * C_ + c0);
      a0 += w[c0 * 9 + ky * 3 + kx] * bf2f((ushort_t)(v & 0xffffu));
      a1 += w[(c0 + 1) * 9 + ky * 3 + kx] * bf2f((ushort_t)(v >> 16));
    }
  }
  float s0 = gamma[c0] * rsqrtf(var[c0] + 1e-5f);
  float s1 = gamma[c0 + 1] * rsqrtf(var[c0 + 1] + 1e-5f);
  float r0 = fmaxf((a0 + bias[c0] - mean[c0]) * s0 + beta[c0], 0.f);
  float r1 = fmaxf((a1 + bias[c0 + 1] - mean[c0 + 1]) * s1 + beta[c0 + 1], 0.f);
  float2* xp = (float2*)&xf[(size_t)bn * C_ + c0];
  float2 old = *xp;
  old.x += r0; old.y += r1;
  *xp = old;
}

extern "C" void kernel_launch(void* const* d_in, const int* in_sizes, int n_in,
                              void* d_out, int out_size, void* d_ws, size_t ws_size,
                              hipStream_t stream) {
  const float* x        = (const float*)d_in[0];
  const float* Wq       = (const float*)d_in[3];
  const float* Wkv      = (const float*)d_in[4];
  const float* an_bias  = (const float*)d_in[5];
  const float* na_bias  = (const float*)d_in[6];
  const float* ah_bias  = (const float*)d_in[7];
  const float* aw_bias  = (const float*)d_in[8];
  const float* ha_bias  = (const float*)d_in[9];
  const float* wa_bias  = (const float*)d_in[10];
  const float* dwc_w    = (const float*)d_in[11];
  const float* dwc_b    = (const float*)d_in[12];
  const float* bn_gamma = (const float*)d_in[13];
  const float* bn_beta  = (const float*)d_in[14];
  const float* bn_mean  = (const float*)d_in[15];
  const float* bn_var   = (const float*)d_in[16];
  const float* base_w   = (const float*)d_in[17];
  const float* spline_w = (const float*)d_in[18];
  const float* spline_s = (const float*)d_in[19];

  char* ws = (char*)d_ws;
  ushort_t* qkvb   = (ushort_t*)(ws + 0);
  ushort_t* xbf    = (ushort_t*)(ws + 86704128);
  ushort_t* wbf    = (ushort_t*)(ws + 115605504);
  ushort_t* bpackb = (ushort_t*)(ws + 117596160);
  float* agent     = (float*)(ws + 123568128);
  float* agent_v   = (float*)(ws + 127180800);
  float* abias     = (float*)(ws + 130793472);
  float* qbias     = (float*)(ws + 132022784);
  float* xf        = (float*)(ws + 133252096);
  float* out       = (float*)d_out;

  convert_x_kernel<<<dim3(2048), dim3(256), 0, stream>>>(x, xbf);
  pack_w_kernel<<<dim3(1024), dim3(256), 0, stream>>>(Wq, Wkv, wbf);
  pack_b_kernel<<<dim3(C_), dim3(256), 0, stream>>>(base_w, spline_w, spline_s, bpackb);
  bias_kernel<<<dim3((HEADS_ * AGENT_ * N_ + 255) / 256), dim3(256), 0, stream>>>(
      an_bias, na_bias, ah_bias, aw_bias, ha_bias, wa_bias, abias, qbias);
  mfma_qkv_kernel<<<dim3(9, 196), dim3(256), 0, stream>>>(xbf, wbf, qkvb);
  agent_pool_kernel<<<dim3(B_ * AGENT_), dim3(C_), 0, stream>>>(qkvb, agent);
  agent_attn2_kernel<<<dim3(2, HEADS_, B_), dim3(256), 0, stream>>>(
      agent, qkvb, abias, agent_v);
  q_attn_kernel<<<dim3(4, HEADS_, B_), dim3(256), 0, stream>>>(
      qkvb, agent, agent_v, qbias, xf);
  dwc_kernel<<<dim3(M_), dim3(288), 0, stream>>>(
      qkvb, dwc_w, dwc_b, bn_gamma, bn_beta, bn_mean, bn_var, xf);
  kan_mfma_kernel<<<dim3(3, 196), dim3(256), 0, stream>>>(xf, bpackb, out);
}

// Round 5
// 721.193 us; speedup vs baseline: 6.6863x; 1.4078x over previous
//
#include <hip/hip_runtime.h>
#include <hip/hip_bf16.h>
#include <math.h>

#define B_ 32
#define N_ 784
#define C_ 576
#define H_ 28
#define W_ 28
#define HEADS_ 8
#define HD_ 72
#define AGENT_ 49
#define M_ (B_ * N_)            // 25088
#define KTOT_ 5184              // 576 silu + 576*8 spline
#define QKVW_ 1728
#define SCALE_ 0.11785113019775793f
#define LDA_ 40                 // padded LDS row stride (elems) for BK=32

typedef unsigned short ushort_t;
typedef __attribute__((ext_vector_type(8))) unsigned short u16x8;
typedef __attribute__((ext_vector_type(8))) __bf16 bf16x8;
typedef __attribute__((ext_vector_type(4))) float f32x4;
typedef __attribute__((ext_vector_type(4))) unsigned u32x4;

__device__ __forceinline__ ushort_t f2bf(float f) {
  union { float f; unsigned u; } v; v.f = f;
  unsigned r = v.u + 0x7fffu + ((v.u >> 16) & 1u);
  return (ushort_t)(r >> 16);
}
__device__ __forceinline__ float bf2f(ushort_t u) {
  union { unsigned u; float f; } v; v.u = ((unsigned)u) << 16;
  return v.f;
}
__device__ __forceinline__ unsigned pack2(float lo, float hi) {
  __bf16 a = (__bf16)lo, b = (__bf16)hi;
  unsigned short ua = __builtin_bit_cast(unsigned short, a);
  unsigned short ub = __builtin_bit_cast(unsigned short, b);
  return (unsigned)ua | ((unsigned)ub << 16);
}

// ---------------- converts / packs ----------------
__global__ __launch_bounds__(256) void convert_x_kernel(
    const float* __restrict__ x, ushort_t* __restrict__ xbf) {
  const int total8 = M_ * C_ / 8;
  for (int i = blockIdx.x * 256 + threadIdx.x; i < total8; i += gridDim.x * 256) {
    f32x4 a = *(const f32x4*)(x + i * 8);
    f32x4 b = *(const f32x4*)(x + i * 8 + 4);
    u16x8 o;
    o[0]=f2bf(a[0]); o[1]=f2bf(a[1]); o[2]=f2bf(a[2]); o[3]=f2bf(a[3]);
    o[4]=f2bf(b[0]); o[5]=f2bf(b[1]); o[6]=f2bf(b[2]); o[7]=f2bf(b[3]);
    *(u16x8*)(xbf + i * 8) = o;
  }
}

__global__ __launch_bounds__(256) void pack_w_kernel(
    const float* __restrict__ Wq, const float* __restrict__ Wkv,
    ushort_t* __restrict__ wbf) {
  int total = QKVW_ * C_;
  for (int i = blockIdx.x * 256 + threadIdx.x; i < total; i += gridDim.x * 256) {
    int j = i / C_, k = i % C_;
    float v = (j < C_) ? Wq[(size_t)j * C_ + k] : Wkv[(size_t)(j - C_) * C_ + k];
    wbf[i] = f2bf(v);
  }
}

__global__ __launch_bounds__(256) void pack_b_kernel(
    const float* __restrict__ base_w, const float* __restrict__ spline_w,
    const float* __restrict__ spline_s, ushort_t* __restrict__ bpackb) {
  int o = blockIdx.x;
  for (int j = threadIdx.x; j < KTOT_; j += 256) {
    float v;
    if (j < C_) {
      v = base_w[(size_t)o * C_ + j];
    } else {
      int jj = j - C_;
      int i = jj >> 3, kk = jj & 7;
      v = spline_w[((size_t)o * C_ + i) * 8 + kk] * spline_s[(size_t)o * C_ + i];
    }
    bpackb[(size_t)o * KTOT_ + j] = f2bf(v);
  }
}

// ---------------- bias precompute ----------------
__device__ __forceinline__ float bilerp7(const float* __restrict__ Bsrc, int y, int x) {
  float sy = y * 0.25f - 0.375f;
  float sx = x * 0.25f - 0.375f;
  float fy0 = floorf(sy), fx0 = floorf(sx);
  int y0 = (int)fy0, x0 = (int)fx0;
  float fy = sy - fy0, fx = sx - fx0;
  int y0c = min(6, max(0, y0)), y1c = min(6, max(0, y0 + 1));
  int x0c = min(6, max(0, x0)), x1c = min(6, max(0, x0 + 1));
  float v00 = Bsrc[y0c * 7 + x0c], v01 = Bsrc[y0c * 7 + x1c];
  float v10 = Bsrc[y1c * 7 + x0c], v11 = Bsrc[y1c * 7 + x1c];
  return (1.f - fy) * ((1.f - fx) * v00 + fx * v01)
       + fy * ((1.f - fx) * v10 + fx * v11);
}

__global__ __launch_bounds__(256) void bias_kernel(
    const float* __restrict__ an_bias, const float* __restrict__ na_bias,
    const float* __restrict__ ah_bias, const float* __restrict__ aw_bias,
    const float* __restrict__ ha_bias, const float* __restrict__ wa_bias,
    float* __restrict__ abias, float* __restrict__ qbias) {
  int idx = blockIdx.x * 256 + threadIdx.x;
  if (idx >= HEADS_ * AGENT_ * N_) return;
  int n = idx % N_;
  int ha = idx / N_;
  int h = ha / AGENT_, a = ha % AGENT_;
  int y = n / W_, x = n % W_;
  float pb1 = bilerp7(an_bias + (size_t)ha * 49, y, x);
  float pb2 = ah_bias[ha * H_ + y] + aw_bias[ha * W_ + x];
  abias[(size_t)ha * N_ + n] = pb1 + pb2;
  float ab1 = bilerp7(na_bias + (size_t)ha * 49, y, x);
  float ab2 = ha_bias[(h * H_ + y) * AGENT_ + a] + wa_bias[(h * W_ + x) * AGENT_ + a];
  qbias[((size_t)h * N_ + n) * AGENT_ + a] = ab1 + ab2;
}

// ---------------- MFMA GEMM: qkv (dbuf, single barrier, padded LDS) ----------
__global__ __launch_bounds__(256, 2) void mfma_qkv_kernel(
    const ushort_t* __restrict__ A, const ushort_t* __restrict__ Bt,
    ushort_t* __restrict__ out) {
  __shared__ ushort_t Asl[2][128 * LDA_];
  __shared__ ushort_t Bsl[2][192 * LDA_];
  const int tid = threadIdx.x;
  const int lane = tid & 63, wid = tid >> 6;
  const int wm = wid >> 1, wn = wid & 1;
  const int m0 = blockIdx.y * 128, n0 = blockIdx.x * 192;
  const int l16 = lane & 15, lq = lane >> 4;

  const int rA = tid >> 1, hA = tid & 1;
  int rB[3], cB[3];
  #pragma unroll
  for (int u = 0; u < 3; ++u) { int it = tid + u * 256; rB[u] = it >> 2; cB[u] = it & 3; }

  const ushort_t* arow = A + (size_t)(m0 + rA) * C_ + hA * 16;

  f32x4 acc[4][6] = {};
  u16x8 ar0, ar1, br[3];

  ar0 = *(const u16x8*)(arow + 0);
  ar1 = *(const u16x8*)(arow + 8);
  #pragma unroll
  for (int u = 0; u < 3; ++u)
    br[u] = *(const u16x8*)(Bt + (size_t)(n0 + rB[u]) * C_ + cB[u] * 8);
  *(u16x8*)&Asl[0][rA * LDA_ + hA * 16] = ar0;
  *(u16x8*)&Asl[0][rA * LDA_ + hA * 16 + 8] = ar1;
  #pragma unroll
  for (int u = 0; u < 3; ++u) *(u16x8*)&Bsl[0][rB[u] * LDA_ + cB[u] * 8] = br[u];
  ar0 = *(const u16x8*)(arow + 32);
  ar1 = *(const u16x8*)(arow + 40);
  #pragma unroll
  for (int u = 0; u < 3; ++u)
    br[u] = *(const u16x8*)(Bt + (size_t)(n0 + rB[u]) * C_ + 32 + cB[u] * 8);
  __syncthreads();

  const int NSTEP = C_ / 32;   // 18
  for (int s = 0; s < NSTEP; ++s) {
    const int cur = s & 1;
    bf16x8 af[4], bfr[6];
    #pragma unroll
    for (int fm = 0; fm < 4; ++fm)
      af[fm] = *(const bf16x8*)&Asl[cur][(wm * 64 + fm * 16 + l16) * LDA_ + lq * 8];
    #pragma unroll
    for (int fn = 0; fn < 6; ++fn)
      bfr[fn] = *(const bf16x8*)&Bsl[cur][(wn * 96 + fn * 16 + l16) * LDA_ + lq * 8];
    #pragma unroll
    for (int fm = 0; fm < 4; ++fm)
      #pragma unroll
      for (int fn = 0; fn < 6; ++fn)
        acc[fm][fn] = __builtin_amdgcn_mfma_f32_16x16x32_bf16(
            af[fm], bfr[fn], acc[fm][fn], 0, 0, 0);
    if (s + 1 < NSTEP) {
      const int nxt = cur ^ 1;
      *(u16x8*)&Asl[nxt][rA * LDA_ + hA * 16] = ar0;
      *(u16x8*)&Asl[nxt][rA * LDA_ + hA * 16 + 8] = ar1;
      #pragma unroll
      for (int u = 0; u < 3; ++u) *(u16x8*)&Bsl[nxt][rB[u] * LDA_ + cB[u] * 8] = br[u];
      if (s + 2 < NSTEP) {
        const int kl = (s + 2) * 32;
        ar0 = *(const u16x8*)(arow + kl);
        ar1 = *(const u16x8*)(arow + kl + 8);
        #pragma unroll
        for (int u = 0; u < 3; ++u)
          br[u] = *(const u16x8*)(Bt + (size_t)(n0 + rB[u]) * C_ + kl + cB[u] * 8);
      }
    }
    __syncthreads();
  }
  #pragma unroll
  for (int fm = 0; fm < 4; ++fm) {
    #pragma unroll
    for (int fn = 0; fn < 6; ++fn) {
      int col = n0 + wn * 96 + fn * 16 + l16;
      #pragma unroll
      for (int r = 0; r < 4; ++r) {
        int row = m0 + wm * 64 + fm * 16 + lq * 4 + r;
        out[(size_t)row * QKVW_ + col] = f2bf(acc[fm][fn][r]);
      }
    }
  }
}

// ---------------- KAN A-operand generation (fast) ----------------
__device__ __forceinline__ u32x4 basesPack(float xv) {
  float s = __fmaf_rn(xv, 2.5f, 5.5f);
  float tf = floorf(s);
  int t = (int)tf;
  float u = s - tf;
  float u2 = u * u, u3 = u2 * u, um = 1.f - u;
  float p0 = u3 * (1.f / 6.f);
  float p1 = (-3.f * u3 + 3.f * u2 + 3.f * u + 1.f) * (1.f / 6.f);
  float p2 = (3.f * u3 - 6.f * u2 + 4.f) * (1.f / 6.f);
  float p3 = um * um * um * (1.f / 6.f);
  unsigned lo = pack2(p3, p2);
  unsigned hi = pack2(p1, p0);
  unsigned cm1 = lo << 16;
  unsigned c1  = (lo >> 16) | (hi << 16);
  unsigned c3  = hi >> 16;
  bool inr = (t >= 0) && (t <= 10);
  u32x4 o;
  #pragma unroll
  for (int j = 0; j < 4; ++j) {
    int d = 3 - t + 2 * j;
    unsigned r = 0u;
    r = (d == -1) ? cm1 : r;
    r = (d == 0)  ? lo  : r;
    r = (d == 1)  ? c1  : r;
    r = (d == 2)  ? hi  : r;
    r = (d == 3)  ? c3  : r;
    o[j] = inr ? r : 0u;
  }
  return o;
}

__device__ __forceinline__ u32x4 siluPack(const float* xv) {
  u32x4 o;
  #pragma unroll
  for (int e = 0; e < 4; ++e) {
    float v0 = xv[2 * e], v1 = xv[2 * e + 1];
    float s0 = v0 / (1.f + __expf(-v0));
    float s1 = v1 / (1.f + __expf(-v1));
    o[e] = pack2(s0, s1);
  }
  return o;
}

// ---------------- KAN MFMA GEMM (dbuf, single barrier, padded LDS) ----------
__global__ __launch_bounds__(256, 2) void kan_mfma_kernel(
    const float* __restrict__ xf, const ushort_t* __restrict__ Bt,
    float* __restrict__ out) {
  __shared__ ushort_t Asl[2][128 * LDA_];
  __shared__ ushort_t Bsl[2][192 * LDA_];
  const int tid = threadIdx.x;
  const int lane = tid & 63, wid = tid >> 6;
  const int wm = wid >> 1, wn = wid & 1;
  const int m0 = blockIdx.y * 128, n0 = blockIdx.x * 192;
  const int l16 = lane & 15, lq = lane >> 4;

  const int rA = tid >> 1, hA = tid & 1;
  int rB[3], cB[3];
  #pragma unroll
  for (int u = 0; u < 3; ++u) { int it = tid + u * 256; rB[u] = it >> 2; cB[u] = it & 3; }

  const float* xfr = xf + (size_t)(m0 + rA) * C_;

  f32x4 acc[4][6] = {};
  float xv[16];
  u16x8 br[3];

  #pragma unroll
  for (int q = 0; q < 4; ++q) {
    f32x4 t4 = *(const f32x4*)(xfr + hA * 16 + q * 4);
    xv[q * 4 + 0] = t4[0]; xv[q * 4 + 1] = t4[1];
    xv[q * 4 + 2] = t4[2]; xv[q * 4 + 3] = t4[3];
  }
  #pragma unroll
  for (int u = 0; u < 3; ++u)
    br[u] = *(const u16x8*)(Bt + (size_t)(n0 + rB[u]) * KTOT_ + cB[u] * 8);
  {
    u32x4 a0 = siluPack(xv), a1 = siluPack(xv + 8);
    *(u32x4*)&Asl[0][rA * LDA_ + hA * 16] = a0;
    *(u32x4*)&Asl[0][rA * LDA_ + hA * 16 + 8] = a1;
    #pragma unroll
    for (int u = 0; u < 3; ++u) *(u16x8*)&Bsl[0][rB[u] * LDA_ + cB[u] * 8] = br[u];
  }
  #pragma unroll
  for (int q = 0; q < 4; ++q) {
    f32x4 t4 = *(const f32x4*)(xfr + 32 + hA * 16 + q * 4);
    xv[q * 4 + 0] = t4[0]; xv[q * 4 + 1] = t4[1];
    xv[q * 4 + 2] = t4[2]; xv[q * 4 + 3] = t4[3];
  }
  #pragma unroll
  for (int u = 0; u < 3; ++u)
    br[u] = *(const u16x8*)(Bt + (size_t)(n0 + rB[u]) * KTOT_ + 32 + cB[u] * 8);
  __syncthreads();

  const int NSTEP = KTOT_ / 32;   // 162
  for (int s = 0; s < NSTEP; ++s) {
    const int cur = s & 1;
    bf16x8 af[4], bfr[6];
    #pragma unroll
    for (int fm = 0; fm < 4; ++fm)
      af[fm] = *(const bf16x8*)&Asl[cur][(wm * 64 + fm * 16 + l16) * LDA_ + lq * 8];
    #pragma unroll
    for (int fn = 0; fn < 6; ++fn)
      bfr[fn] = *(const bf16x8*)&Bsl[cur][(wn * 96 + fn * 16 + l16) * LDA_ + lq * 8];
    #pragma unroll
    for (int fm = 0; fm < 4; ++fm)
      #pragma unroll
      for (int fn = 0; fn < 6; ++fn)
        acc[fm][fn] = __builtin_amdgcn_mfma_f32_16x16x32_bf16(
            af[fm], bfr[fn], acc[fm][fn], 0, 0, 0);
    if (s + 1 < NSTEP) {
      const int nxt = cur ^ 1;
      const int kg = (s + 1) * 32;
      u32x4 a0, a1;
      if (kg < C_) { a0 = siluPack(xv); a1 = siluPack(xv + 8); }
      else         { a0 = basesPack(xv[0]); a1 = basesPack(xv[1]); }
      *(u32x4*)&Asl[nxt][rA * LDA_ + hA * 16] = a0;
      *(u32x4*)&Asl[nxt][rA * LDA_ + hA * 16 + 8] = a1;
      #pragma unroll
      for (int u = 0; u < 3; ++u) *(u16x8*)&Bsl[nxt][rB[u] * LDA_ + cB[u] * 8] = br[u];
      if (s + 2 < NSTEP) {
        const int kl = (s + 2) * 32;
        if (kl < C_) {
          #pragma unroll
          for (int q = 0; q < 4; ++q) {
            f32x4 t4 = *(const f32x4*)(xfr + kl + hA * 16 + q * 4);
            xv[q * 4 + 0] = t4[0]; xv[q * 4 + 1] = t4[1];
            xv[q * 4 + 2] = t4[2]; xv[q * 4 + 3] = t4[3];
          }
        } else {
          int i0 = ((kl - C_) >> 3) + hA * 2;
          xv[0] = xfr[i0];
          xv[1] = xfr[i0 + 1];
        }
        #pragma unroll
        for (int u = 0; u < 3; ++u)
          br[u] = *(const u16x8*)(Bt + (size_t)(n0 + rB[u]) * KTOT_ + kl + cB[u] * 8);
      }
    }
    __syncthreads();
  }
  #pragma unroll
  for (int fm = 0; fm < 4; ++fm) {
    #pragma unroll
    for (int fn = 0; fn < 6; ++fn) {
      int col = n0 + wn * 96 + fn * 16 + l16;
      #pragma unroll
      for (int r = 0; r < 4; ++r) {
        int row = m0 + wm * 64 + fm * 16 + lq * 4 + r;
        out[(size_t)row * C_ + col] = acc[fm][fn][r];
      }
    }
  }
}

// ---------------- agent pooling ----------------
__global__ __launch_bounds__(576) void agent_pool_kernel(
    const ushort_t* __restrict__ qkvb, float* __restrict__ agent) {
  int ba = blockIdx.x;
  int b = ba / AGENT_, a = ba % AGENT_;
  int ay = a / 7, ax = a % 7;
  int ch = threadIdx.x;
  float s = 0.f;
  #pragma unroll
  for (int i2 = 0; i2 < 4; ++i2)
    #pragma unroll
    for (int i4 = 0; i4 < 4; ++i4)
      s += bf2f(qkvb[((size_t)b * N_ + (ay * 4 + i2) * W_ + (ax * 4 + i4)) * QKVW_ + ch]);
  agent[(size_t)ba * C_ + ch] = s * 0.0625f;
}

// ---------------- agent attention v3: MFMA flash, one block per (b,h) -------
// waves: 4, each owns a 16-agent M-tile. 7 chunks of 112 tokens.
#define AKS_ 104   // A/K LDS row stride (elems)
#define VTS_ 136   // Vt/P LDS row stride (elems)
__global__ __launch_bounds__(256) void agent_attn_mfma_kernel(
    const float* __restrict__ agent, const ushort_t* __restrict__ qkvb,
    const float* __restrict__ abias, float* __restrict__ agent_v) {
  __shared__ ushort_t A_lds[64 * AKS_];      // [agent][d]    13.3 KB
  __shared__ ushort_t K_lds[112 * AKS_];     // [token][d]    23.3 KB
  __shared__ ushort_t Vt_lds[80 * VTS_];     // [d][token]    21.8 KB
  __shared__ ushort_t P_lds[4][16 * VTS_];   // per-wave [a][token] 17.4 KB
  const int tid = threadIdx.x;
  const int lane = tid & 63, wid = tid >> 6;
  const int l16 = lane & 15, lq = lane >> 4;
  const int b = blockIdx.x >> 3, h = blockIdx.x & 7;

  // ---- one-time zero fills (padding must be 0, not garbage: 0*NaN = NaN) ----
  for (int i = tid; i < 64 * AKS_; i += 256) A_lds[i] = 0;
  for (int i = tid; i < 112 * 32; i += 256) {
    int r = i >> 5, cc = 72 + (i & 31);
    K_lds[r * AKS_ + cc] = 0;
  }
  for (int i = tid; i < 80 * VTS_; i += 256) Vt_lds[i] = 0;
  for (int i = tid; i < 4 * 16 * 24; i += 256) {
    int w = i / (16 * 24), rest = i % (16 * 24);
    int r = rest / 24, cc = 112 + rest % 24;
    P_lds[w][r * VTS_ + cc] = 0;
  }
  // stage agents (49 x 72)
  for (int i = tid; i < AGENT_ * HD_; i += 256) {
    int a = i / HD_, d = i % HD_;
    A_lds[a * AKS_ + d] = f2bf(agent[((size_t)b * AGENT_ + a) * C_ + h * HD_ + d]);
  }

  // staging indices: 112 rows x 9 u16x8 per matrix
  int srow[4], scol[4]; bool sval[4];
  #pragma unroll
  for (int i = 0; i < 4; ++i) {
    int idx = tid + i * 256;
    srow[i] = idx / 9; scol[i] = idx % 9;
    sval[i] = idx < 1008;
  }
  const ushort_t* kbase = qkvb + (size_t)b * N_ * QKVW_ + C_ + h * HD_;
  const ushort_t* vbase = qkvb + (size_t)b * N_ * QKVW_ + 2 * C_ + h * HD_;

  u16x8 kreg[4], vreg[4];
  #pragma unroll
  for (int i = 0; i < 4; ++i) {
    if (sval[i]) {
      kreg[i] = *(const u16x8*)(kbase + (size_t)srow[i] * QKVW_ + scol[i] * 8);
      vreg[i] = *(const u16x8*)(vbase + (size_t)srow[i] * QKVW_ + scol[i] * 8);
    }
  }
  #pragma unroll
  for (int i = 0; i < 4; ++i) {
    if (sval[i]) {
      *(u16x8*)&K_lds[srow[i] * AKS_ + scol[i] * 8] = kreg[i];
      #pragma unroll
      for (int e = 0; e < 8; ++e)
        Vt_lds[(scol[i] * 8 + e) * VTS_ + srow[i]] = vreg[i][e];
    }
  }
  __syncthreads();

  // flash state (rows = wid*16 + lq*4 + r)
  float m_r[4] = {-1e30f, -1e30f, -1e30f, -1e30f};
  float l_r[4] = {};
  f32x4 O[5] = {};
  const float* bias_base[4];
  #pragma unroll
  for (int r = 0; r < 4; ++r) {
    int a = wid * 16 + lq * 4 + r;
    a = min(a, AGENT_ - 1);
    bias_base[r] = abias + ((size_t)h * AGENT_ + a) * N_;
  }

  for (int c = 0; c < 7; ++c) {
    // prefetch next chunk into regs
    if (c < 6) {
      const size_t off = (size_t)(c + 1) * 112 * QKVW_;
      #pragma unroll
      for (int i = 0; i < 4; ++i) {
        if (sval[i]) {
          kreg[i] = *(const u16x8*)(kbase + off + (size_t)srow[i] * QKVW_ + scol[i] * 8);
          vreg[i] = *(const u16x8*)(vbase + off + (size_t)srow[i] * QKVW_ + scol[i] * 8);
        }
      }
    }
    // S = A . K^T   (K padded 72->96 with zeros both sides)
    f32x4 sacc[7] = {};
    #pragma unroll
    for (int ks = 0; ks < 3; ++ks) {
      bf16x8 af = *(const bf16x8*)&A_lds[(wid * 16 + l16) * AKS_ + ks * 32 + lq * 8];
      #pragma unroll
      for (int nt = 0; nt < 7; ++nt) {
        bf16x8 bf = *(const bf16x8*)&K_lds[(nt * 16 + l16) * AKS_ + ks * 32 + lq * 8];
        sacc[nt] = __builtin_amdgcn_mfma_f32_16x16x32_bf16(af, bf, sacc[nt], 0, 0, 0);
      }
    }
    // logits + row max
    float cmax[4] = {-1e30f, -1e30f, -1e30f, -1e30f};
    const int nb = c * 112 + l16;
    #pragma unroll
    for (int nt = 0; nt < 7; ++nt)
      #pragma unroll
      for (int r = 0; r < 4; ++r) {
        float lg = sacc[nt][r] * SCALE_ + bias_base[r][nb + nt * 16];
        sacc[nt][r] = lg;
        cmax[r] = fmaxf(cmax[r], lg);
      }
    #pragma unroll
    for (int off = 1; off < 16; off <<= 1)
      #pragma unroll
      for (int r = 0; r < 4; ++r)
        cmax[r] = fmaxf(cmax[r], __shfl_xor(cmax[r], off));
    float scl[4], rs[4];
    #pragma unroll
    for (int r = 0; r < 4; ++r) {
      float nm = fmaxf(m_r[r], cmax[r]);
      scl[r] = __expf(m_r[r] - nm);
      m_r[r] = nm;
      rs[r] = 0.f;
    }
    // P = exp(S - m), write per-wave P tile
    #pragma unroll
    for (int nt = 0; nt < 7; ++nt)
      #pragma unroll
      for (int r = 0; r < 4; ++r) {
        float p = __expf(sacc[nt][r] - m_r[r]);
        rs[r] += p;
        P_lds[wid][(lq * 4 + r) * VTS_ + nt * 16 + l16] = f2bf(p);
      }
    #pragma unroll
    for (int off = 1; off < 16; off <<= 1)
      #pragma unroll
      for (int r = 0; r < 4; ++r)
        rs[r] += __shfl_xor(rs[r], off);
    #pragma unroll
    for (int r = 0; r < 4; ++r) l_r[r] = l_r[r] * scl[r] + rs[r];
    #pragma unroll
    for (int nt = 0; nt < 5; ++nt)
      #pragma unroll
      for (int r = 0; r < 4; ++r) O[nt][r] *= scl[r];
    // O += P . V   (token K padded 112->128 with zero P & zero Vt)
    #pragma unroll
    for (int ks = 0; ks < 4; ++ks) {
      bf16x8 pf = *(const bf16x8*)&P_lds[wid][l16 * VTS_ + ks * 32 + lq * 8];
      #pragma unroll
      for (int nt = 0; nt < 5; ++nt) {
        bf16x8 vf = *(const bf16x8*)&Vt_lds[(nt * 16 + l16) * VTS_ + ks * 32 + lq * 8];
        O[nt] = __builtin_amdgcn_mfma_f32_16x16x32_bf16(pf, vf, O[nt], 0, 0, 0);
      }
    }
    __syncthreads();
    if (c < 6) {
      #pragma unroll
      for (int i = 0; i < 4; ++i) {
        if (sval[i]) {
          *(u16x8*)&K_lds[srow[i] * AKS_ + scol[i] * 8] = kreg[i];
          #pragma unroll
          for (int e = 0; e < 8; ++e)
            Vt_lds[(scol[i] * 8 + e) * VTS_ + srow[i]] = vreg[i][e];
        }
      }
      __syncthreads();
    }
  }
  // epilogue
  float inv[4];
  #pragma unroll
  for (int r = 0; r < 4; ++r) inv[r] = 1.f / l_r[r];
  #pragma unroll
  for (int nt = 0; nt < 5; ++nt) {
    int d = nt * 16 + l16;
    if (d >= HD_) continue;
    #pragma unroll
    for (int r = 0; r < 4; ++r) {
      int a = wid * 16 + lq * 4 + r;
      if (a < AGENT_)
        agent_v[(((size_t)b * HEADS_ + h) * AGENT_ + a) * HD_ + d] = O[nt][r] * inv[r];
    }
  }
}

// ---------------- q attention ----------------
__global__ __launch_bounds__(256) void q_attn_kernel(
    const ushort_t* __restrict__ qkvb, const float* __restrict__ agent,
    const float* __restrict__ agent_v, const float* __restrict__ qbias,
    float* __restrict__ xf) {
  __shared__ float ag_t[HD_ * 52];
  __shared__ float av_t[HD_ * 52];
  const int tid = threadIdx.x;
  const int h = blockIdx.y, b = blockIdx.z;
  for (int t = tid; t < AGENT_ * HD_; t += 256) {
    int a = t / HD_, d = t % HD_;
    ag_t[d * 52 + a] = agent[((size_t)b * AGENT_ + a) * C_ + h * HD_ + d];
    av_t[d * 52 + a] = agent_v[(((size_t)b * HEADS_ + h) * AGENT_ + a) * HD_ + d];
  }
  __syncthreads();
  const int n = blockIdx.x * 256 + tid;
  if (n >= N_) return;
  const ushort_t* qp = qkvb + ((size_t)b * N_ + n) * QKVW_ + h * HD_;
  const float* qb = qbias + ((size_t)h * N_ + n) * AGENT_;
  float lg[AGENT_];
  #pragma unroll
  for (int a = 0; a < AGENT_; ++a) lg[a] = qb[a];
  for (int d = 0; d < HD_; ++d) {
    float qd = bf2f(qp[d]) * SCALE_;
    #pragma unroll
    for (int a = 0; a < AGENT_; ++a) lg[a] += qd * ag_t[d * 52 + a];
  }
  float mx = -1e30f;
  #pragma unroll
  for (int a = 0; a < AGENT_; ++a) mx = fmaxf(mx, lg[a]);
  float s = 0.f;
  #pragma unroll
  for (int a = 0; a < AGENT_; ++a) { lg[a] = __expf(lg[a] - mx); s += lg[a]; }
  float inv = 1.f / s;
  #pragma unroll
  for (int a = 0; a < AGENT_; ++a) lg[a] *= inv;
  float* op = xf + ((size_t)b * N_ + n) * C_ + h * HD_;
  for (int d = 0; d < HD_; ++d) {
    float acc = 0.f;
    #pragma unroll
    for (int a = 0; a < AGENT_; ++a) acc += lg[a] * av_t[d * 52 + a];
    op[d] = acc;
  }
}

// ---------------- depthwise conv + BN + ReLU (2ch/thread) ----------------
__global__ __launch_bounds__(288) void dwc_kernel(
    const ushort_t* __restrict__ qkvb, const float* __restrict__ w,
    const float* __restrict__ bias, const float* __restrict__ gamma,
    const float* __restrict__ beta, const float* __restrict__ mean,
    const float* __restrict__ var, float* __restrict__ xf) {
  const int bn = blockIdx.x;
  const int b = bn / N_, n = bn % N_;
  const int y = n / W_, x = n % W_;
  const int c0 = threadIdx.x * 2;
  float a0 = 0.f, a1 = 0.f;
  #pragma unroll
  for (int ky = 0; ky < 3; ++ky) {
    int yy = y + ky - 1;
    if (yy < 0 || yy >= H_) continue;
    #pragma unroll
    for (int kx = 0; kx < 3; ++kx) {
      int xx = x + kx - 1;
      if (xx < 0 || xx >= W_) continue;
      unsigned v = *(const unsigned*)(qkvb + ((size_t)b * N_ + yy * W_ + xx) * QKVW_ + 2 * C_ + c0);
      a0 += w[c0 * 9 + ky * 3 + kx] * bf2f((ushort_t)(v & 0xffffu));
      a1 += w[(c0 + 1) * 9 + ky * 3 + kx] * bf2f((ushort_t)(v >> 16));
    }
  }
  float s0 = gamma[c0] * rsqrtf(var[c0] + 1e-5f);
  float s1 = gamma[c0 + 1] * rsqrtf(var[c0 + 1] + 1e-5f);
  float r0 = fmaxf((a0 + bias[c0] - mean[c0]) * s0 + beta[c0], 0.f);
  float r1 = fmaxf((a1 + bias[c0 + 1] - mean[c0 + 1]) * s1 + beta[c0 + 1], 0.f);
  float2* xp = (float2*)&xf[(size_t)bn * C_ + c0];
  float2 old = *xp;
  old.x += r0; old.y += r1;
  *xp = old;
}

extern "C" void kernel_launch(void* const* d_in, const int* in_sizes, int n_in,
                              void* d_out, int out_size, void* d_ws, size_t ws_size,
                              hipStream_t stream) {
  const float* x        = (const float*)d_in[0];
  const float* Wq       = (const float*)d_in[3];
  const float* Wkv      = (const float*)d_in[4];
  const float* an_bias  = (const float*)d_in[5];
  const float* na_bias  = (const float*)d_in[6];
  const float* ah_bias  = (const float*)d_in[7];
  const float* aw_bias  = (const float*)d_in[8];
  const float* ha_bias  = (const float*)d_in[9];
  const float* wa_bias  = (const float*)d_in[10];
  const float* dwc_w    = (const float*)d_in[11];
  const float* dwc_b    = (const float*)d_in[12];
  const float* bn_gamma = (const float*)d_in[13];
  const float* bn_beta  = (const float*)d_in[14];
  const float* bn_mean  = (const float*)d_in[15];
  const float* bn_var   = (const float*)d_in[16];
  const float* base_w   = (const float*)d_in[17];
  const float* spline_w = (const float*)d_in[18];
  const float* spline_s = (const float*)d_in[19];

  char* ws = (char*)d_ws;
  ushort_t* qkvb   = (ushort_t*)(ws + 0);
  ushort_t* xbf    = (ushort_t*)(ws + 86704128);
  ushort_t* wbf    = (ushort_t*)(ws + 115605504);
  ushort_t* bpackb = (ushort_t*)(ws + 117596160);
  float* agent     = (float*)(ws + 123568128);
  float* agent_v   = (float*)(ws + 127180800);
  float* abias     = (float*)(ws + 130793472);
  float* qbias     = (float*)(ws + 132022784);
  float* xf        = (float*)(ws + 133252096);
  float* out       = (float*)d_out;

  convert_x_kernel<<<dim3(2048), dim3(256), 0, stream>>>(x, xbf);
  pack_w_kernel<<<dim3(1024), dim3(256), 0, stream>>>(Wq, Wkv, wbf);
  pack_b_kernel<<<dim3(C_), dim3(256), 0, stream>>>(base_w, spline_w, spline_s, bpackb);
  bias_kernel<<<dim3((HEADS_ * AGENT_ * N_ + 255) / 256), dim3(256), 0, stream>>>(
      an_bias, na_bias, ah_bias, aw_bias, ha_bias, wa_bias, abias, qbias);
  mfma_qkv_kernel<<<dim3(9, 196), dim3(256), 0, stream>>>(xbf, wbf, qkvb);
  agent_pool_kernel<<<dim3(B_ * AGENT_), dim3(C_), 0, stream>>>(qkvb, agent);
  agent_attn_mfma_kernel<<<dim3(B_ * HEADS_), dim3(256), 0, stream>>>(
      agent, qkvb, abias, agent_v);
  q_attn_kernel<<<dim3(4, HEADS_, B_), dim3(256), 0, stream>>>(
      qkvb, agent, agent_v, qbias, xf);
  dwc_kernel<<<dim3(M_), dim3(288), 0, stream>>>(
      qkvb, dwc_w, dwc_b, bn_gamma, bn_beta, bn_mean, bn_var, xf);
  kan_mfma_kernel<<<dim3(3, 196), dim3(256), 0, stream>>>(xf, bpackb, out);
}

// Round 6
// 672.029 us; speedup vs baseline: 7.1754x; 1.0732x over previous
//
#include <hip/hip_runtime.h>
#include <hip/hip_bf16.h>
#include <math.h>

#define B_ 32
#define N_ 784
#define C_ 576
#define H_ 28
#define W_ 28
#define HEADS_ 8
#define HD_ 72
#define AGENT_ 49
#define M_ (B_ * N_)            // 25088
#define KTOT_ 5184              // 576 silu + 576*8 spline
#define QKVW_ 1728
#define SCALE_ 0.11785113019775793f
#define LDA_ 40                 // padded LDS row stride (elems) for BK=32

typedef unsigned short ushort_t;
typedef __attribute__((ext_vector_type(8))) unsigned short u16x8;
typedef __attribute__((ext_vector_type(8))) __bf16 bf16x8;
typedef __attribute__((ext_vector_type(4))) float f32x4;
typedef __attribute__((ext_vector_type(4))) unsigned u32x4;

__device__ __forceinline__ ushort_t f2bf(float f) {
  union { float f; unsigned u; } v; v.f = f;
  unsigned r = v.u + 0x7fffu + ((v.u >> 16) & 1u);
  return (ushort_t)(r >> 16);
}
__device__ __forceinline__ float bf2f(ushort_t u) {
  union { unsigned u; float f; } v; v.u = ((unsigned)u) << 16;
  return v.f;
}
__device__ __forceinline__ unsigned pack2(float lo, float hi) {
  __bf16 a = (__bf16)lo, b = (__bf16)hi;
  unsigned short ua = __builtin_bit_cast(unsigned short, a);
  unsigned short ub = __builtin_bit_cast(unsigned short, b);
  return (unsigned)ua | ((unsigned)ub << 16);
}

// ---------------- converts / packs ----------------
__global__ __launch_bounds__(256) void convert_x_kernel(
    const float* __restrict__ x, ushort_t* __restrict__ xbf) {
  const int total8 = M_ * C_ / 8;
  for (int i = blockIdx.x * 256 + threadIdx.x; i < total8; i += gridDim.x * 256) {
    f32x4 a = *(const f32x4*)(x + i * 8);
    f32x4 b = *(const f32x4*)(x + i * 8 + 4);
    u16x8 o;
    o[0]=f2bf(a[0]); o[1]=f2bf(a[1]); o[2]=f2bf(a[2]); o[3]=f2bf(a[3]);
    o[4]=f2bf(b[0]); o[5]=f2bf(b[1]); o[6]=f2bf(b[2]); o[7]=f2bf(b[3]);
    *(u16x8*)(xbf + i * 8) = o;
  }
}

__global__ __launch_bounds__(256) void pack_w_kernel(
    const float* __restrict__ Wq, const float* __restrict__ Wkv,
    ushort_t* __restrict__ wbf) {
  int total = QKVW_ * C_;
  for (int i = blockIdx.x * 256 + threadIdx.x; i < total; i += gridDim.x * 256) {
    int j = i / C_, k = i % C_;
    float v = (j < C_) ? Wq[(size_t)j * C_ + k] : Wkv[(size_t)(j - C_) * C_ + k];
    wbf[i] = f2bf(v);
  }
}

__global__ __launch_bounds__(256) void pack_b_kernel(
    const float* __restrict__ base_w, const float* __restrict__ spline_w,
    const float* __restrict__ spline_s, ushort_t* __restrict__ bpackb) {
  int o = blockIdx.x;
  for (int j = threadIdx.x; j < KTOT_; j += 256) {
    float v;
    if (j < C_) {
      v = base_w[(size_t)o * C_ + j];
    } else {
      int jj = j - C_;
      int i = jj >> 3, kk = jj & 7;
      v = spline_w[((size_t)o * C_ + i) * 8 + kk] * spline_s[(size_t)o * C_ + i];
    }
    bpackb[(size_t)o * KTOT_ + j] = f2bf(v);
  }
}

// ---------------- bias precompute ----------------
__device__ __forceinline__ float bilerp7(const float* __restrict__ Bsrc, int y, int x) {
  float sy = y * 0.25f - 0.375f;
  float sx = x * 0.25f - 0.375f;
  float fy0 = floorf(sy), fx0 = floorf(sx);
  int y0 = (int)fy0, x0 = (int)fx0;
  float fy = sy - fy0, fx = sx - fx0;
  int y0c = min(6, max(0, y0)), y1c = min(6, max(0, y0 + 1));
  int x0c = min(6, max(0, x0)), x1c = min(6, max(0, x0 + 1));
  float v00 = Bsrc[y0c * 7 + x0c], v01 = Bsrc[y0c * 7 + x1c];
  float v10 = Bsrc[y1c * 7 + x0c], v11 = Bsrc[y1c * 7 + x1c];
  return (1.f - fy) * ((1.f - fx) * v00 + fx * v01)
       + fy * ((1.f - fx) * v10 + fx * v11);
}

__global__ __launch_bounds__(256) void bias_kernel(
    const float* __restrict__ an_bias, const float* __restrict__ na_bias,
    const float* __restrict__ ah_bias, const float* __restrict__ aw_bias,
    const float* __restrict__ ha_bias, const float* __restrict__ wa_bias,
    float* __restrict__ abias, float* __restrict__ qbias) {
  int idx = blockIdx.x * 256 + threadIdx.x;
  if (idx >= HEADS_ * AGENT_ * N_) return;
  int n = idx % N_;
  int ha = idx / N_;
  int h = ha / AGENT_, a = ha % AGENT_;
  int y = n / W_, x = n % W_;
  float pb1 = bilerp7(an_bias + (size_t)ha * 49, y, x);
  float pb2 = ah_bias[ha * H_ + y] + aw_bias[ha * W_ + x];
  abias[(size_t)ha * N_ + n] = pb1 + pb2;
  float ab1 = bilerp7(na_bias + (size_t)ha * 49, y, x);
  float ab2 = ha_bias[(h * H_ + y) * AGENT_ + a] + wa_bias[(h * W_ + x) * AGENT_ + a];
  qbias[((size_t)h * N_ + n) * AGENT_ + a] = ab1 + ab2;
}

// ---------------- MFMA GEMM: qkv (8 waves, dbuf, XCD swizzle) ----------
// grid: 1764 = 196 row-tiles x 9 col-tiles (col fastest); 1764 = 8*220+4
__global__ __launch_bounds__(512, 4) void mfma_qkv_kernel(
    const ushort_t* __restrict__ A, const ushort_t* __restrict__ Bt,
    ushort_t* __restrict__ out) {
  __shared__ ushort_t Asl[2][128 * LDA_];
  __shared__ ushort_t Bsl[2][192 * LDA_];
  const int tid = threadIdx.x;
  const int lane = tid & 63, wid = tid >> 6;
  const int wm = wid >> 2, wn = wid & 3;
  const int l16 = lane & 15, lq = lane >> 4;

  int lin = blockIdx.x;
  const int q = 220, r = 4;          // 1764 = 8*220+4
  int xcd = lin & 7;
  int wg = (xcd < r ? xcd * (q + 1) : r * (q + 1) + (xcd - r) * q) + (lin >> 3);
  const int m0 = (wg / 9) * 128, n0 = (wg % 9) * 192;

  const int rA = tid >> 2, hA = tid & 3;         // A: 128 rows x 4 groups of 8
  const int rB0 = tid >> 2, cB0 = tid & 3;       // B slots 0..511
  const int rB1 = 128 + (tid >> 2), cB1 = tid & 3; // B slots 512..767 (tid<256)
  const bool hasB1 = tid < 256;

  const ushort_t* arow = A + (size_t)(m0 + rA) * C_ + hA * 8;
  const ushort_t* brow0 = Bt + (size_t)(n0 + rB0) * C_ + cB0 * 8;
  const ushort_t* brow1 = Bt + (size_t)(n0 + rB1) * C_ + cB1 * 8;

  f32x4 acc[4][3] = {};
  u16x8 ar, br0, br1;

  // step 0 load + write buf0
  ar = *(const u16x8*)(arow);
  br0 = *(const u16x8*)(brow0);
  if (hasB1) br1 = *(const u16x8*)(brow1);
  *(u16x8*)&Asl[0][rA * LDA_ + hA * 8] = ar;
  *(u16x8*)&Bsl[0][rB0 * LDA_ + cB0 * 8] = br0;
  if (hasB1) *(u16x8*)&Bsl[0][rB1 * LDA_ + cB1 * 8] = br1;
  // step 1 load
  ar = *(const u16x8*)(arow + 32);
  br0 = *(const u16x8*)(brow0 + 32);
  if (hasB1) br1 = *(const u16x8*)(brow1 + 32);
  __syncthreads();

  const int NSTEP = C_ / 32;   // 18
  for (int s = 0; s < NSTEP; ++s) {
    const int cur = s & 1;
    bf16x8 af[4], bfr[3];
    #pragma unroll
    for (int fm = 0; fm < 4; ++fm)
      af[fm] = *(const bf16x8*)&Asl[cur][(wm * 64 + fm * 16 + l16) * LDA_ + lq * 8];
    #pragma unroll
    for (int fn = 0; fn < 3; ++fn)
      bfr[fn] = *(const bf16x8*)&Bsl[cur][(wn * 48 + fn * 16 + l16) * LDA_ + lq * 8];
    #pragma unroll
    for (int fm = 0; fm < 4; ++fm)
      #pragma unroll
      for (int fn = 0; fn < 3; ++fn)
        acc[fm][fn] = __builtin_amdgcn_mfma_f32_16x16x32_bf16(
            af[fm], bfr[fn], acc[fm][fn], 0, 0, 0);
    if (s + 1 < NSTEP) {
      const int nxt = cur ^ 1;
      *(u16x8*)&Asl[nxt][rA * LDA_ + hA * 8] = ar;
      *(u16x8*)&Bsl[nxt][rB0 * LDA_ + cB0 * 8] = br0;
      if (hasB1) *(u16x8*)&Bsl[nxt][rB1 * LDA_ + cB1 * 8] = br1;
      if (s + 2 < NSTEP) {
        const int kl = (s + 2) * 32;
        ar = *(const u16x8*)(arow + kl);
        br0 = *(const u16x8*)(brow0 + kl);
        if (hasB1) br1 = *(const u16x8*)(brow1 + kl);
      }
    }
    __syncthreads();
  }
  #pragma unroll
  for (int fm = 0; fm < 4; ++fm) {
    #pragma unroll
    for (int fn = 0; fn < 3; ++fn) {
      int col = n0 + wn * 48 + fn * 16 + l16;
      #pragma unroll
      for (int r2 = 0; r2 < 4; ++r2) {
        int row = m0 + wm * 64 + fm * 16 + lq * 4 + r2;
        out[(size_t)row * QKVW_ + col] = f2bf(acc[fm][fn][r2]);
      }
    }
  }
}

// ---------------- KAN A-operand generation ----------------
__device__ __forceinline__ u32x4 basesPack(float xv) {
  float s = __fmaf_rn(xv, 2.5f, 5.5f);
  float tf = floorf(s);
  int t = (int)tf;
  float u = s - tf;
  float u2 = u * u, u3 = u2 * u, um = 1.f - u;
  float p0 = u3 * (1.f / 6.f);
  float p1 = (-3.f * u3 + 3.f * u2 + 3.f * u + 1.f) * (1.f / 6.f);
  float p2 = (3.f * u3 - 6.f * u2 + 4.f) * (1.f / 6.f);
  float p3 = um * um * um * (1.f / 6.f);
  unsigned lo = pack2(p3, p2);
  unsigned hi = pack2(p1, p0);
  unsigned cm1 = lo << 16;
  unsigned c1  = (lo >> 16) | (hi << 16);
  unsigned c3  = hi >> 16;
  bool inr = (t >= 0) && (t <= 10);
  u32x4 o;
  #pragma unroll
  for (int j = 0; j < 4; ++j) {
    int d = 3 - t + 2 * j;
    unsigned rr = 0u;
    rr = (d == -1) ? cm1 : rr;
    rr = (d == 0)  ? lo  : rr;
    rr = (d == 1)  ? c1  : rr;
    rr = (d == 2)  ? hi  : rr;
    rr = (d == 3)  ? c3  : rr;
    o[j] = inr ? rr : 0u;
  }
  return o;
}

__device__ __forceinline__ u32x4 siluPack(const float* xv) {
  u32x4 o;
  #pragma unroll
  for (int e = 0; e < 4; ++e) {
    float v0 = xv[2 * e], v1 = xv[2 * e + 1];
    float s0 = v0 / (1.f + __expf(-v0));
    float s1 = v1 / (1.f + __expf(-v1));
    o[e] = pack2(s0, s1);
  }
  return o;
}

// ---------------- KAN MFMA GEMM (8 waves, dbuf, XCD swizzle) ----------
// grid: 588 = 196 row-tiles x 3 col-tiles (col fastest); 588 = 8*73+4
__global__ __launch_bounds__(512, 4) void kan_mfma_kernel(
    const float* __restrict__ xf, const ushort_t* __restrict__ Bt,
    float* __restrict__ out) {
  __shared__ ushort_t Asl[2][128 * LDA_];
  __shared__ ushort_t Bsl[2][192 * LDA_];
  const int tid = threadIdx.x;
  const int lane = tid & 63, wid = tid >> 6;
  const int wm = wid >> 2, wn = wid & 3;
  const int l16 = lane & 15, lq = lane >> 4;

  int lin = blockIdx.x;
  const int q = 73, r = 4;           // 588 = 8*73+4
  int xcd = lin & 7;
  int wg = (xcd < r ? xcd * (q + 1) : r * (q + 1) + (xcd - r) * q) + (lin >> 3);
  const int m0 = (wg / 3) * 128, n0 = (wg % 3) * 192;

  const int rA = tid >> 2, hA = tid & 3;
  const int rB0 = tid >> 2, cB0 = tid & 3;
  const int rB1 = 128 + (tid >> 2), cB1 = tid & 3;
  const bool hasB1 = tid < 256;

  const float* xfr = xf + (size_t)(m0 + rA) * C_;
  const ushort_t* brow0 = Bt + (size_t)(n0 + rB0) * KTOT_ + cB0 * 8;
  const ushort_t* brow1 = Bt + (size_t)(n0 + rB1) * KTOT_ + cB1 * 8;

  f32x4 acc[4][3] = {};
  float xv[8];
  u16x8 br0, br1;

  // step 0 load (silu region: 8 floats)
  {
    f32x4 a = *(const f32x4*)(xfr + hA * 8);
    f32x4 b = *(const f32x4*)(xfr + hA * 8 + 4);
    xv[0]=a[0]; xv[1]=a[1]; xv[2]=a[2]; xv[3]=a[3];
    xv[4]=b[0]; xv[5]=b[1]; xv[6]=b[2]; xv[7]=b[3];
  }
  br0 = *(const u16x8*)(brow0);
  if (hasB1) br1 = *(const u16x8*)(brow1);
  // gen+write step0
  *(u32x4*)&Asl[0][rA * LDA_ + hA * 8] = siluPack(xv);
  *(u16x8*)&Bsl[0][rB0 * LDA_ + cB0 * 8] = br0;
  if (hasB1) *(u16x8*)&Bsl[0][rB1 * LDA_ + cB1 * 8] = br1;
  // step 1 load
  {
    f32x4 a = *(const f32x4*)(xfr + 32 + hA * 8);
    f32x4 b = *(const f32x4*)(xfr + 32 + hA * 8 + 4);
    xv[0]=a[0]; xv[1]=a[1]; xv[2]=a[2]; xv[3]=a[3];
    xv[4]=b[0]; xv[5]=b[1]; xv[6]=b[2]; xv[7]=b[3];
  }
  br0 = *(const u16x8*)(brow0 + 32);
  if (hasB1) br1 = *(const u16x8*)(brow1 + 32);
  __syncthreads();

  const int NSTEP = KTOT_ / 32;   // 162
  for (int s = 0; s < NSTEP; ++s) {
    const int cur = s & 1;
    bf16x8 af[4], bfr[3];
    #pragma unroll
    for (int fm = 0; fm < 4; ++fm)
      af[fm] = *(const bf16x8*)&Asl[cur][(wm * 64 + fm * 16 + l16) * LDA_ + lq * 8];
    #pragma unroll
    for (int fn = 0; fn < 3; ++fn)
      bfr[fn] = *(const bf16x8*)&Bsl[cur][(wn * 48 + fn * 16 + l16) * LDA_ + lq * 8];
    #pragma unroll
    for (int fm = 0; fm < 4; ++fm)
      #pragma unroll
      for (int fn = 0; fn < 3; ++fn)
        acc[fm][fn] = __builtin_amdgcn_mfma_f32_16x16x32_bf16(
            af[fm], bfr[fn], acc[fm][fn], 0, 0, 0);
    if (s + 1 < NSTEP) {
      const int nxt = cur ^ 1;
      const int kg = (s + 1) * 32;
      u32x4 a0 = (kg < C_) ? siluPack(xv) : basesPack(xv[0]);
      *(u32x4*)&Asl[nxt][rA * LDA_ + hA * 8] = a0;
      *(u16x8*)&Bsl[nxt][rB0 * LDA_ + cB0 * 8] = br0;
      if (hasB1) *(u16x8*)&Bsl[nxt][rB1 * LDA_ + cB1 * 8] = br1;
      if (s + 2 < NSTEP) {
        const int kl = (s + 2) * 32;
        if (kl < C_) {
          f32x4 a = *(const f32x4*)(xfr + kl + hA * 8);
          f32x4 b = *(const f32x4*)(xfr + kl + hA * 8 + 4);
          xv[0]=a[0]; xv[1]=a[1]; xv[2]=a[2]; xv[3]=a[3];
          xv[4]=b[0]; xv[5]=b[1]; xv[6]=b[2]; xv[7]=b[3];
        } else {
          xv[0] = xfr[((kl - C_) >> 3) + hA];
        }
        br0 = *(const u16x8*)(brow0 + kl);
        if (hasB1) br1 = *(const u16x8*)(brow1 + kl);
      }
    }
    __syncthreads();
  }
  #pragma unroll
  for (int fm = 0; fm < 4; ++fm) {
    #pragma unroll
    for (int fn = 0; fn < 3; ++fn) {
      int col = n0 + wn * 48 + fn * 16 + l16;
      #pragma unroll
      for (int r2 = 0; r2 < 4; ++r2) {
        int row = m0 + wm * 64 + fm * 16 + lq * 4 + r2;
        out[(size_t)row * C_ + col] = acc[fm][fn][r2];
      }
    }
  }
}

// ---------------- agent pooling ----------------
__global__ __launch_bounds__(576) void agent_pool_kernel(
    const ushort_t* __restrict__ qkvb, float* __restrict__ agent) {
  int ba = blockIdx.x;
  int b = ba / AGENT_, a = ba % AGENT_;
  int ay = a / 7, ax = a % 7;
  int ch = threadIdx.x;
  float s = 0.f;
  #pragma unroll
  for (int i2 = 0; i2 < 4; ++i2)
    #pragma unroll
    for (int i4 = 0; i4 < 4; ++i4)
      s += bf2f(qkvb[((size_t)b * N_ + (ay * 4 + i2) * W_ + (ax * 4 + i4)) * QKVW_ + ch]);
  agent[(size_t)ba * C_ + ch] = s * 0.0625f;
}

// ---------------- agent attention v3: MFMA flash, one block per (b,h) -------
#define AKS_ 104
#define VTS_ 136
__global__ __launch_bounds__(256) void agent_attn_mfma_kernel(
    const float* __restrict__ agent, const ushort_t* __restrict__ qkvb,
    const float* __restrict__ abias, float* __restrict__ agent_v) {
  __shared__ ushort_t A_lds[64 * AKS_];
  __shared__ ushort_t K_lds[112 * AKS_];
  __shared__ ushort_t Vt_lds[80 * VTS_];
  __shared__ ushort_t P_lds[4][16 * VTS_];
  const int tid = threadIdx.x;
  const int lane = tid & 63, wid = tid >> 6;
  const int l16 = lane & 15, lq = lane >> 4;
  const int b = blockIdx.x >> 3, h = blockIdx.x & 7;

  for (int i = tid; i < 64 * AKS_; i += 256) A_lds[i] = 0;
  for (int i = tid; i < 112 * 32; i += 256) {
    int r = i >> 5, cc = 72 + (i & 31);
    K_lds[r * AKS_ + cc] = 0;
  }
  for (int i = tid; i < 80 * VTS_; i += 256) Vt_lds[i] = 0;
  for (int i = tid; i < 4 * 16 * 24; i += 256) {
    int w = i / (16 * 24), rest = i % (16 * 24);
    int r = rest / 24, cc = 112 + rest % 24;
    P_lds[w][r * VTS_ + cc] = 0;
  }
  for (int i = tid; i < AGENT_ * HD_; i += 256) {
    int a = i / HD_, d = i % HD_;
    A_lds[a * AKS_ + d] = f2bf(agent[((size_t)b * AGENT_ + a) * C_ + h * HD_ + d]);
  }

  int srow[4], scol[4]; bool sval[4];
  #pragma unroll
  for (int i = 0; i < 4; ++i) {
    int idx = tid + i * 256;
    srow[i] = idx / 9; scol[i] = idx % 9;
    sval[i] = idx < 1008;
  }
  const ushort_t* kbase = qkvb + (size_t)b * N_ * QKVW_ + C_ + h * HD_;
  const ushort_t* vbase = qkvb + (size_t)b * N_ * QKVW_ + 2 * C_ + h * HD_;

  u16x8 kreg[4], vreg[4];
  #pragma unroll
  for (int i = 0; i < 4; ++i) {
    if (sval[i]) {
      kreg[i] = *(const u16x8*)(kbase + (size_t)srow[i] * QKVW_ + scol[i] * 8);
      vreg[i] = *(const u16x8*)(vbase + (size_t)srow[i] * QKVW_ + scol[i] * 8);
    }
  }
  #pragma unroll
  for (int i = 0; i < 4; ++i) {
    if (sval[i]) {
      *(u16x8*)&K_lds[srow[i] * AKS_ + scol[i] * 8] = kreg[i];
      #pragma unroll
      for (int e = 0; e < 8; ++e)
        Vt_lds[(scol[i] * 8 + e) * VTS_ + srow[i]] = vreg[i][e];
    }
  }
  __syncthreads();

  float m_r[4] = {-1e30f, -1e30f, -1e30f, -1e30f};
  float l_r[4] = {};
  f32x4 O[5] = {};
  const float* bias_base[4];
  #pragma unroll
  for (int r = 0; r < 4; ++r) {
    int a = wid * 16 + lq * 4 + r;
    a = min(a, AGENT_ - 1);
    bias_base[r] = abias + ((size_t)h * AGENT_ + a) * N_;
  }

  for (int c = 0; c < 7; ++c) {
    if (c < 6) {
      const size_t off = (size_t)(c + 1) * 112 * QKVW_;
      #pragma unroll
      for (int i = 0; i < 4; ++i) {
        if (sval[i]) {
          kreg[i] = *(const u16x8*)(kbase + off + (size_t)srow[i] * QKVW_ + scol[i] * 8);
          vreg[i] = *(const u16x8*)(vbase + off + (size_t)srow[i] * QKVW_ + scol[i] * 8);
        }
      }
    }
    f32x4 sacc[7] = {};
    #pragma unroll
    for (int ks = 0; ks < 3; ++ks) {
      bf16x8 af = *(const bf16x8*)&A_lds[(wid * 16 + l16) * AKS_ + ks * 32 + lq * 8];
      #pragma unroll
      for (int nt = 0; nt < 7; ++nt) {
        bf16x8 bf = *(const bf16x8*)&K_lds[(nt * 16 + l16) * AKS_ + ks * 32 + lq * 8];
        sacc[nt] = __builtin_amdgcn_mfma_f32_16x16x32_bf16(af, bf, sacc[nt], 0, 0, 0);
      }
    }
    float cmax[4] = {-1e30f, -1e30f, -1e30f, -1e30f};
    const int nb = c * 112 + l16;
    #pragma unroll
    for (int nt = 0; nt < 7; ++nt)
      #pragma unroll
      for (int r = 0; r < 4; ++r) {
        float lg = sacc[nt][r] * SCALE_ + bias_base[r][nb + nt * 16];
        sacc[nt][r] = lg;
        cmax[r] = fmaxf(cmax[r], lg);
      }
    #pragma unroll
    for (int off = 1; off < 16; off <<= 1)
      #pragma unroll
      for (int r = 0; r < 4; ++r)
        cmax[r] = fmaxf(cmax[r], __shfl_xor(cmax[r], off));
    float scl[4], rs[4];
    #pragma unroll
    for (int r = 0; r < 4; ++r) {
      float nm = fmaxf(m_r[r], cmax[r]);
      scl[r] = __expf(m_r[r] - nm);
      m_r[r] = nm;
      rs[r] = 0.f;
    }
    #pragma unroll
    for (int nt = 0; nt < 7; ++nt)
      #pragma unroll
      for (int r = 0; r < 4; ++r) {
        float p = __expf(sacc[nt][r] - m_r[r]);
        rs[r] += p;
        P_lds[wid][(lq * 4 + r) * VTS_ + nt * 16 + l16] = f2bf(p);
      }
    #pragma unroll
    for (int off = 1; off < 16; off <<= 1)
      #pragma unroll
      for (int r = 0; r < 4; ++r)
        rs[r] += __shfl_xor(rs[r], off);
    #pragma unroll
    for (int r = 0; r < 4; ++r) l_r[r] = l_r[r] * scl[r] + rs[r];
    #pragma unroll
    for (int nt = 0; nt < 5; ++nt)
      #pragma unroll
      for (int r = 0; r < 4; ++r) O[nt][r] *= scl[r];
    #pragma unroll
    for (int ks = 0; ks < 4; ++ks) {
      bf16x8 pf = *(const bf16x8*)&P_lds[wid][l16 * VTS_ + ks * 32 + lq * 8];
      #pragma unroll
      for (int nt = 0; nt < 5; ++nt) {
        bf16x8 vf = *(const bf16x8*)&Vt_lds[(nt * 16 + l16) * VTS_ + ks * 32 + lq * 8];
        O[nt] = __builtin_amdgcn_mfma_f32_16x16x32_bf16(pf, vf, O[nt], 0, 0, 0);
      }
    }
    __syncthreads();
    if (c < 6) {
      #pragma unroll
      for (int i = 0; i < 4; ++i) {
        if (sval[i]) {
          *(u16x8*)&K_lds[srow[i] * AKS_ + scol[i] * 8] = kreg[i];
          #pragma unroll
          for (int e = 0; e < 8; ++e)
            Vt_lds[(scol[i] * 8 + e) * VTS_ + srow[i]] = vreg[i][e];
        }
      }
      __syncthreads();
    }
  }
  float inv[4];
  #pragma unroll
  for (int r = 0; r < 4; ++r) inv[r] = 1.f / l_r[r];
  #pragma unroll
  for (int nt = 0; nt < 5; ++nt) {
    int d = nt * 16 + l16;
    if (d >= HD_) continue;
    #pragma unroll
    for (int r = 0; r < 4; ++r) {
      int a = wid * 16 + lq * 4 + r;
      if (a < AGENT_)
        agent_v[(((size_t)b * HEADS_ + h) * AGENT_ + a) * HD_ + d] = O[nt][r] * inv[r];
    }
  }
}

// ---------------- q attention ----------------
__global__ __launch_bounds__(256) void q_attn_kernel(
    const ushort_t* __restrict__ qkvb, const float* __restrict__ agent,
    const float* __restrict__ agent_v, const float* __restrict__ qbias,
    float* __restrict__ xf) {
  __shared__ float ag_t[HD_ * 52];
  __shared__ float av_t[HD_ * 52];
  const int tid = threadIdx.x;
  const int h = blockIdx.y, b = blockIdx.z;
  for (int t = tid; t < AGENT_ * HD_; t += 256) {
    int a = t / HD_, d = t % HD_;
    ag_t[d * 52 + a] = agent[((size_t)b * AGENT_ + a) * C_ + h * HD_ + d];
    av_t[d * 52 + a] = agent_v[(((size_t)b * HEADS_ + h) * AGENT_ + a) * HD_ + d];
  }
  __syncthreads();
  const int n = blockIdx.x * 256 + tid;
  if (n >= N_) return;
  const ushort_t* qp = qkvb + ((size_t)b * N_ + n) * QKVW_ + h * HD_;
  const float* qb = qbias + ((size_t)h * N_ + n) * AGENT_;
  float lg[AGENT_];
  #pragma unroll
  for (int a = 0; a < AGENT_; ++a) lg[a] = qb[a];
  for (int d = 0; d < HD_; ++d) {
    float qd = bf2f(qp[d]) * SCALE_;
    #pragma unroll
    for (int a = 0; a < AGENT_; ++a) lg[a] += qd * ag_t[d * 52 + a];
  }
  float mx = -1e30f;
  #pragma unroll
  for (int a = 0; a < AGENT_; ++a) mx = fmaxf(mx, lg[a]);
  float s = 0.f;
  #pragma unroll
  for (int a = 0; a < AGENT_; ++a) { lg[a] = __expf(lg[a] - mx); s += lg[a]; }
  float inv = 1.f / s;
  #pragma unroll
  for (int a = 0; a < AGENT_; ++a) lg[a] *= inv;
  float* op = xf + ((size_t)b * N_ + n) * C_ + h * HD_;
  for (int d = 0; d < HD_; ++d) {
    float acc = 0.f;
    #pragma unroll
    for (int a = 0; a < AGENT_; ++a) acc += lg[a] * av_t[d * 52 + a];
    op[d] = acc;
  }
}

// ---------------- depthwise conv + BN + ReLU (2ch/thread) ----------------
__global__ __launch_bounds__(288) void dwc_kernel(
    const ushort_t* __restrict__ qkvb, const float* __restrict__ w,
    const float* __restrict__ bias, const float* __restrict__ gamma,
    const float* __restrict__ beta, const float* __restrict__ mean,
    const float* __restrict__ var, float* __restrict__ xf) {
  const int bn = blockIdx.x;
  const int b = bn / N_, n = bn % N_;
  const int y = n / W_, x = n % W_;
  const int c0 = threadIdx.x * 2;
  float a0 = 0.f, a1 = 0.f;
  #pragma unroll
  for (int ky = 0; ky < 3; ++ky) {
    int yy = y + ky - 1;
    if (yy < 0 || yy >= H_) continue;
    #pragma unroll
    for (int kx = 0; kx < 3; ++kx) {
      int xx = x + kx - 1;
      if (xx < 0 || xx >= W_) continue;
      unsigned v = *(const unsigned*)(qkvb + ((size_t)b * N_ + yy * W_ + xx) * QKVW_ + 2 * C_ + c0);
      a0 += w[c0 * 9 + ky * 3 + kx] * bf2f((ushort_t)(v & 0xffffu));
      a1 += w[(c0 + 1) * 9 + ky * 3 + kx] * bf2f((ushort_t)(v >> 16));
    }
  }
  float s0 = gamma[c0] * rsqrtf(var[c0] + 1e-5f);
  float s1 = gamma[c0 + 1] * rsqrtf(var[c0 + 1] + 1e-5f);
  float r0 = fmaxf((a0 + bias[c0] - mean[c0]) * s0 + beta[c0], 0.f);
  float r1 = fmaxf((a1 + bias[c0 + 1] - mean[c0 + 1]) * s1 + beta[c0 + 1], 0.f);
  float2* xp = (float2*)&xf[(size_t)bn * C_ + c0];
  float2 old = *xp;
  old.x += r0; old.y += r1;
  *xp = old;
}

extern "C" void kernel_launch(void* const* d_in, const int* in_sizes, int n_in,
                              void* d_out, int out_size, void* d_ws, size_t ws_size,
                              hipStream_t stream) {
  const float* x        = (const float*)d_in[0];
  const float* Wq       = (const float*)d_in[3];
  const float* Wkv      = (const float*)d_in[4];
  const float* an_bias  = (const float*)d_in[5];
  const float* na_bias  = (const float*)d_in[6];
  const float* ah_bias  = (const float*)d_in[7];
  const float* aw_bias  = (const float*)d_in[8];
  const float* ha_bias  = (const float*)d_in[9];
  const float* wa_bias  = (const float*)d_in[10];
  const float* dwc_w    = (const float*)d_in[11];
  const float* dwc_b    = (const float*)d_in[12];
  const float* bn_gamma = (const float*)d_in[13];
  const float* bn_beta  = (const float*)d_in[14];
  const float* bn_mean  = (const float*)d_in[15];
  const float* bn_var   = (const float*)d_in[16];
  const float* base_w   = (const float*)d_in[17];
  const float* spline_w = (const float*)d_in[18];
  const float* spline_s = (const float*)d_in[19];

  char* ws = (char*)d_ws;
  ushort_t* qkvb   = (ushort_t*)(ws + 0);
  ushort_t* xbf    = (ushort_t*)(ws + 86704128);
  ushort_t* wbf    = (ushort_t*)(ws + 115605504);
  ushort_t* bpackb = (ushort_t*)(ws + 117596160);
  float* agent     = (float*)(ws + 123568128);
  float* agent_v   = (float*)(ws + 127180800);
  float* abias     = (float*)(ws + 130793472);
  float* qbias     = (float*)(ws + 132022784);
  float* xf        = (float*)(ws + 133252096);
  float* out       = (float*)d_out;

  convert_x_kernel<<<dim3(2048), dim3(256), 0, stream>>>(x, xbf);
  pack_w_kernel<<<dim3(1024), dim3(256), 0, stream>>>(Wq, Wkv, wbf);
  pack_b_kernel<<<dim3(C_), dim3(256), 0, stream>>>(base_w, spline_w, spline_s, bpackb);
  bias_kernel<<<dim3((HEADS_ * AGENT_ * N_ + 255) / 256), dim3(256), 0, stream>>>(
      an_bias, na_bias, ah_bias, aw_bias, ha_bias, wa_bias, abias, qbias);
  mfma_qkv_kernel<<<dim3(1764), dim3(512), 0, stream>>>(xbf, wbf, qkvb);
  agent_pool_kernel<<<dim3(B_ * AGENT_), dim3(C_), 0, stream>>>(qkvb, agent);
  agent_attn_mfma_kernel<<<dim3(B_ * HEADS_), dim3(256), 0, stream>>>(
      agent, qkvb, abias, agent_v);
  q_attn_kernel<<<dim3(4, HEADS_, B_), dim3(256), 0, stream>>>(
      qkvb, agent, agent_v, qbias, xf);
  dwc_kernel<<<dim3(M_), dim3(288), 0, stream>>>(
      qkvb, dwc_w, dwc_b, bn_gamma, bn_beta, bn_mean, bn_var, xf);
  kan_mfma_kernel<<<dim3(588), dim3(512), 0, stream>>>(xf, bpackb, out);
}